// Round 2
// baseline (1884.756 us; speedup 1.0000x reference)
//
#include <hip/hip_runtime.h>
#include <cstdint>
#include <cstddef>

// Problem constants (match reference)
#define NS 4000
#define NG 50000
#define NE 250000
#define DIM 128

// ---------------------------------------------------------------------------
// Y[M,N] (fp32) = X[M,128] @ W[128,N] + b[N]     (all fp32)
// Block = 256 threads. Each thread computes 4 adjacent outputs (float4 W load).
// X rows for the block are staged in LDS (cooperative float4 load).
// ---------------------------------------------------------------------------
template <int N>
__global__ __launch_bounds__(256) void rowgemm(const float* __restrict__ X,
                                               const float* __restrict__ W,
                                               const float* __restrict__ B,
                                               float* __restrict__ Y, int M) {
  constexpr int TPR = N / 4;        // threads per row
  constexpr int R = 256 / TPR;      // rows per block
  __shared__ float xs[R * DIM];
  int row0 = blockIdx.x * R;
  for (int i = threadIdx.x * 4; i < R * DIM; i += 1024) {
    int rr = i >> 7;                // i / DIM
    int gr = row0 + rr;
    float4 v = make_float4(0.f, 0.f, 0.f, 0.f);
    if (gr < M) v = *reinterpret_cast<const float4*>(X + (size_t)gr * DIM + (i & 127));
    *reinterpret_cast<float4*>(xs + i) = v;
  }
  __syncthreads();
  int r = threadIdx.x / TPR;
  int n0 = (threadIdx.x % TPR) * 4;
  int m = row0 + r;
  if (m >= M) return;
  const float* xrow = xs + r * DIM;
  float4 acc = make_float4(0.f, 0.f, 0.f, 0.f);
#pragma unroll 8
  for (int k = 0; k < DIM; k++) {
    float xk = xrow[k];
    float4 w = *reinterpret_cast<const float4*>(W + (size_t)k * N + n0);
    acc.x = fmaf(xk, w.x, acc.x);
    acc.y = fmaf(xk, w.y, acc.y);
    acc.z = fmaf(xk, w.z, acc.z);
    acc.w = fmaf(xk, w.w, acc.w);
  }
  float4 b = *reinterpret_cast<const float4*>(B + n0);
  acc.x += b.x; acc.y += b.y; acc.z += b.z; acc.w += b.w;
  *reinterpret_cast<float4*>(Y + (size_t)m * N + n0) = acc;
}

// ---------------------------------------------------------------------------
// Edge pass for one relation. One 64-lane wave per edge.
// NC = 4*C channels; lane handles VEC = NC/64 contiguous channels;
// each head spans exactly 16 lanes (C/VEC == 16 for both C=32 and C=64).
// Softmax max-shift skipped (logits tiny; softmax is shift-invariant).
// Accumulates unnormalized  sum_e exp(logit_eh) * xl[src]  and per-(dst,h)
// denominators with device atomics; finalize divides.
// ---------------------------------------------------------------------------
template <int C>
__global__ void edge_pass(const int* __restrict__ src, const int* __restrict__ dst,
                          const float* __restrict__ ea, const float* __restrict__ We,
                          const float* __restrict__ att,
                          const float* __restrict__ xl, const float* __restrict__ xr,
                          float* __restrict__ outacc, float* __restrict__ denom) {
  constexpr int NC = 4 * C;
  constexpr int VEC = NC / 64;
  int gtid = blockIdx.x * blockDim.x + threadIdx.x;
  int wid = gtid >> 6;
  int lane = threadIdx.x & 63;
  int nw = (gridDim.x * blockDim.x) >> 6;
  for (int e = wid; e < NE; e += nw) {
    int s = src[e];
    int d = dst[e];
    float eav = ea[e];
    float xlv[VEC], xrv[VEC], wev[VEC], atv[VEC];
    const float* xls = xl + (size_t)s * NC + lane * VEC;
    const float* xrd = xr + (size_t)d * NC + lane * VEC;
    if constexpr (VEC == 2) {
      *reinterpret_cast<float2*>(xlv) = *reinterpret_cast<const float2*>(xls);
      *reinterpret_cast<float2*>(xrv) = *reinterpret_cast<const float2*>(xrd);
      *reinterpret_cast<float2*>(wev) = *reinterpret_cast<const float2*>(We + lane * VEC);
      *reinterpret_cast<float2*>(atv) = *reinterpret_cast<const float2*>(att + lane * VEC);
    } else {
      *reinterpret_cast<float4*>(xlv) = *reinterpret_cast<const float4*>(xls);
      *reinterpret_cast<float4*>(xrv) = *reinterpret_cast<const float4*>(xrd);
      *reinterpret_cast<float4*>(wev) = *reinterpret_cast<const float4*>(We + lane * VEC);
      *reinterpret_cast<float4*>(atv) = *reinterpret_cast<const float4*>(att + lane * VEC);
    }
    float p = 0.f;
#pragma unroll
    for (int v = 0; v < VEC; v++) {
      float mm = xlv[v] + xrv[v] + eav * wev[v];
      mm = mm > 0.f ? mm : 0.2f * mm;              // leaky_relu(., 0.2)
      p = fmaf(mm, atv[v], p);
    }
    // reduce logit across the 16 lanes of this head
    p += __shfl_xor(p, 1);
    p += __shfl_xor(p, 2);
    p += __shfl_xor(p, 4);
    p += __shfl_xor(p, 8);
    float ex = __expf(p);
    if ((lane & 15) == 0) atomicAdd(denom + (size_t)d * 4 + (lane >> 4), ex);
    float* oa = outacc + (size_t)d * NC + lane * VEC;
#pragma unroll
    for (int v = 0; v < VEC; v++) atomicAdd(oa + v, ex * xlv[v]);
  }
}

// ---------------------------------------------------------------------------
// Finalize concat-mode layer-1 output in place (fp32):
//   x = relu(acc/denom + bo [+ sl tiled across heads])
// NC = 128, C = 32, H = 4. Empty-destination guard: denom==0 -> 0.
// ---------------------------------------------------------------------------
__global__ void fin_concat(float* __restrict__ x, const float* __restrict__ den,
                           const float* __restrict__ bo, const float* __restrict__ sl,
                           int n) {
  int idx = blockIdx.x * blockDim.x + threadIdx.x;
  if (idx >= n * 128) return;
  int i = idx >> 7;
  int j = idx & 127;
  float dd = den[i * 4 + (j >> 5)];
  float v = dd > 0.f ? x[idx] / dd : 0.f;
  v += bo[j];
  if (sl) v += sl[i * 32 + (j & 31)];
  x[idx] = v > 0.f ? v : 0.f;
}

// ---------------------------------------------------------------------------
// Final output: out[i,c] = relu( mean_h(acc[i,h,c]/den[i,h]) + bo[c] + sl3[i,c] )
// ---------------------------------------------------------------------------
__global__ void fin_out(const float* __restrict__ acc, const float* __restrict__ den,
                        const float* __restrict__ bo, const float* __restrict__ sl,
                        float* __restrict__ out, int n) {
  int idx = blockIdx.x * blockDim.x + threadIdx.x;
  if (idx >= n * 64) return;
  int i = idx >> 6;
  int c = idx & 63;
  float v = 0.f;
#pragma unroll
  for (int h = 0; h < 4; h++) {
    float dd = den[i * 4 + h];
    if (dd > 0.f) v += acc[(size_t)i * 256 + h * 64 + c] / dd;
  }
  v = 0.25f * v + bo[c] + sl[idx];
  out[idx] = v > 0.f ? v : 0.f;
}

// ---------------------------------------------------------------------------

static inline int nblk(long long threads) { return (int)((threads + 255) / 256); }
static inline int nrow(int M, int R) { return (M + R - 1) / R; }

extern "C" void kernel_launch(void* const* d_in, const int* in_sizes, int n_in,
                              void* d_out, int out_size, void* d_ws, size_t ws_size,
                              hipStream_t stream) {
  const float* x_mrna = (const float*)d_in[0];
  const float* x_gene = (const float*)d_in[1];
  const int* sg_src = (const int*)d_in[2];
  const int* sg_dst = (const int*)d_in[3];
  const int* gs_src = (const int*)d_in[4];
  const int* gs_dst = (const int*)d_in[5];
  const float* ea_sg = (const float*)d_in[6];
  const float* ea_gs = (const float*)d_in[7];
  const float* Wl1_sg = (const float*)d_in[8];
  const float* bl1_sg = (const float*)d_in[9];
  const float* Wr1_sg = (const float*)d_in[10];
  const float* br1_sg = (const float*)d_in[11];
  const float* We1_sg = (const float*)d_in[12];
  const float* att1_sg = (const float*)d_in[13];
  const float* bo1_sg = (const float*)d_in[14];
  const float* Wl1_gs = (const float*)d_in[15];
  const float* bl1_gs = (const float*)d_in[16];
  const float* Wr1_gs = (const float*)d_in[17];
  const float* br1_gs = (const float*)d_in[18];
  const float* We1_gs = (const float*)d_in[19];
  const float* att1_gs = (const float*)d_in[20];
  const float* bo1_gs = (const float*)d_in[21];
  const float* Wl3_gs = (const float*)d_in[22];
  const float* bl3_gs = (const float*)d_in[23];
  const float* Wr3_gs = (const float*)d_in[24];
  const float* br3_gs = (const float*)d_in[25];
  const float* We3_gs = (const float*)d_in[26];
  const float* att3_gs = (const float*)d_in[27];
  const float* bo3_gs = (const float*)d_in[28];
  const float* Wsl1 = (const float*)d_in[29];
  const float* bsl1 = (const float*)d_in[30];
  const float* Wsl3 = (const float*)d_in[31];
  const float* bsl3 = (const float*)d_in[32];

  // ---- workspace arena (fp32 offsets). Phase-4 buffers alias dead phase-1
  // buffers. Accumulator region [14080000, 22248000) is contiguous -> one memset.
  float* ws = (float*)d_ws;
  float* xl1_sg = ws + 0;         // [4000 *128]
  float* xr1_sg = ws + 512000;    // [50000*128]
  float* xl1_gs = ws + 6912000;   // [50000*128]
  float* xr1_gs = ws + 13312000;  // [4000 *128]
  float* sl1    = ws + 13824000;  // [4000 * 32]
  float* xl3    = ws + 0;         // [50000*256] (aliases xl1_sg/xr1_sg/xl1_gs head)
  float* xr3    = ws + 12800000;  // [4000 *256] (aliases xl1_gs tail/xr1_gs)
  float* sl3    = ws + 13824000;  // [4000 * 64] (aliases sl1, consumed before)
  float* x1_gene = ws + 14080000; // [50000*128] accumulator -> value
  float* den_sg  = ws + 20480000; // [50000*4]
  float* x1_mrna = ws + 20680000; // [4000 *128]
  float* den_g1  = ws + 21192000; // [4000 *4]
  float* out3    = ws + 21208000; // [4000 *4*64]
  float* den_g3  = ws + 22232000; // [4000 *4]
  // total: 22248000 floats = ~85 MB

  // zero all accumulators (ws is poisoned 0xAA before every timed call)
  hipMemsetAsync(x1_gene, 0, (size_t)8168000 * sizeof(float), stream);

  // ---- phase 1: node GEMMs (layer 1) ----
  rowgemm<128><<<nrow(NS, 8), 256, 0, stream>>>(x_mrna, Wl1_sg, bl1_sg, xl1_sg, NS);
  rowgemm<128><<<nrow(NG, 8), 256, 0, stream>>>(x_gene, Wr1_sg, br1_sg, xr1_sg, NG);
  rowgemm<128><<<nrow(NG, 8), 256, 0, stream>>>(x_gene, Wl1_gs, bl1_gs, xl1_gs, NG);
  rowgemm<128><<<nrow(NS, 8), 256, 0, stream>>>(x_mrna, Wr1_gs, br1_gs, xr1_gs, NS);
  rowgemm<32><<<nrow(NS, 32), 256, 0, stream>>>(x_mrna, Wsl1, bsl1, sl1, NS);

  // ---- phase 2: layer-1 edge passes (one wave per edge) ----
  edge_pass<32><<<62500, 256, 0, stream>>>(sg_src, sg_dst, ea_sg, We1_sg, att1_sg,
                                           xl1_sg, xr1_sg, x1_gene, den_sg);
  edge_pass<32><<<62500, 256, 0, stream>>>(gs_src, gs_dst, ea_gs, We1_gs, att1_gs,
                                           xl1_gs, xr1_gs, x1_mrna, den_g1);

  // ---- phase 3: finalize layer-1 node features (relu, biases, self-loop tile) ----
  fin_concat<<<nblk((long long)NG * 128), 256, 0, stream>>>(x1_gene, den_sg, bo1_sg,
                                                            (const float*)nullptr, NG);
  fin_concat<<<nblk((long long)NS * 128), 256, 0, stream>>>(x1_mrna, den_g1, bo1_gs, sl1, NS);

  // ---- phase 4: node GEMMs (layer 3) ----
  rowgemm<256><<<nrow(NG, 4), 256, 0, stream>>>(x1_gene, Wl3_gs, bl3_gs, xl3, NG);
  rowgemm<256><<<nrow(NS, 4), 256, 0, stream>>>(x1_mrna, Wr3_gs, br3_gs, xr3, NS);
  rowgemm<64><<<nrow(NS, 16), 256, 0, stream>>>(x1_mrna, Wsl3, bsl3, sl3, NS);

  // ---- phase 5: layer-3 edge pass ----
  edge_pass<64><<<62500, 256, 0, stream>>>(gs_src, gs_dst, ea_gs, We3_gs, att3_gs,
                                           xl3, xr3, out3, den_g3);

  // ---- phase 6: head mean + self-loop + relu -> fp32 output ----
  fin_out<<<nblk((long long)NS * 64), 256, 0, stream>>>(out3, den_g3, bo3_gs, sl3,
                                                        (float*)d_out, NS);
}

// Round 3
// 808.016 us; speedup vs baseline: 2.3326x; 2.3326x over previous
//
#include <hip/hip_runtime.h>
#include <cstdint>
#include <cstddef>

// Problem constants (match reference)
#define NS 4000
#define NG 50000
#define NE 250000
#define DIM 128

// ---------------------------------------------------------------------------
// Y[M,N] (fp32) = X[M,128] @ W[128,N] + b[N]     (all fp32)
// Block = 256 threads; 4 adjacent outputs/thread (float4 W loads); X rows in LDS.
// ---------------------------------------------------------------------------
template <int N>
__global__ __launch_bounds__(256) void rowgemm(const float* __restrict__ X,
                                               const float* __restrict__ W,
                                               const float* __restrict__ B,
                                               float* __restrict__ Y, int M) {
  constexpr int TPR = N / 4;        // threads per row
  constexpr int R = 256 / TPR;      // rows per block
  __shared__ float xs[R * DIM];
  int row0 = blockIdx.x * R;
  for (int i = threadIdx.x * 4; i < R * DIM; i += 1024) {
    int gr = row0 + (i >> 7);
    float4 v = make_float4(0.f, 0.f, 0.f, 0.f);
    if (gr < M) v = *reinterpret_cast<const float4*>(X + (size_t)gr * DIM + (i & 127));
    *reinterpret_cast<float4*>(xs + i) = v;
  }
  __syncthreads();
  int r = threadIdx.x / TPR;
  int n0 = (threadIdx.x % TPR) * 4;
  int m = row0 + r;
  if (m >= M) return;
  const float* xrow = xs + r * DIM;
  float4 acc = make_float4(0.f, 0.f, 0.f, 0.f);
#pragma unroll 8
  for (int k = 0; k < DIM; k++) {
    float xk = xrow[k];
    float4 w = *reinterpret_cast<const float4*>(W + (size_t)k * N + n0);
    acc.x = fmaf(xk, w.x, acc.x);
    acc.y = fmaf(xk, w.y, acc.y);
    acc.z = fmaf(xk, w.z, acc.z);
    acc.w = fmaf(xk, w.w, acc.w);
  }
  float4 b = *reinterpret_cast<const float4*>(B + n0);
  acc.x += b.x; acc.y += b.y; acc.z += b.z; acc.w += b.w;
  *reinterpret_cast<float4*>(Y + (size_t)m * N + n0) = acc;
}

// ---------------------------------------------------------------------------
// CSR build: histogram -> exclusive scan -> permutation scatter
// ---------------------------------------------------------------------------
__global__ void hist_kernel(const int* __restrict__ dst, int* __restrict__ cnt) {
  int e = blockIdx.x * blockDim.x + threadIdx.x;
  if (e < NE) atomicAdd(cnt + dst[e], 1);
}

// single-block exclusive scan, wave-shuffle based (2 syncs per 1024-chunk)
__global__ __launch_bounds__(1024) void exscan(const int* __restrict__ cnt,
                                               int* __restrict__ rp, int n) {
  __shared__ int wsum[16];
  __shared__ int carry_s;
  int lane = threadIdx.x & 63;
  int w = threadIdx.x >> 6;
  if (threadIdx.x == 0) carry_s = 0;
  __syncthreads();
  for (int base = 0; base < n; base += 1024) {
    int i = base + threadIdx.x;
    int v = (i < n) ? cnt[i] : 0;
    int x = v;                                   // inclusive wave scan
#pragma unroll
    for (int off = 1; off < 64; off <<= 1) {
      int y = __shfl_up(x, off);
      if (lane >= off) x += y;
    }
    if (lane == 63) wsum[w] = x;
    __syncthreads();
    if (w == 0 && lane < 16) {                   // scan the 16 wave sums
      int s = wsum[lane];
#pragma unroll
      for (int off = 1; off < 16; off <<= 1) {
        int y = __shfl_up(s, off);
        if (lane >= off) s += y;
      }
      wsum[lane] = s;
    }
    __syncthreads();
    int wpre = (w == 0) ? 0 : wsum[w - 1];
    int incl = x + wpre;
    int carry = carry_s;
    if (i < n) rp[i] = carry + incl - v;         // exclusive
    int total = wsum[15];
    __syncthreads();
    if (threadIdx.x == 0) carry_s = carry + total;
    __syncthreads();
  }
  if (threadIdx.x == 0) rp[n] = carry_s;
}

__global__ void scatter_kernel(const int* __restrict__ dst, const int* __restrict__ rp,
                               int* __restrict__ cur, int* __restrict__ perm) {
  int e = blockIdx.x * blockDim.x + threadIdx.x;
  if (e >= NE) return;
  int d = dst[e];
  int pos = atomicAdd(cur + d, 1);
  perm[rp[d] + pos] = e;
}

// ---------------------------------------------------------------------------
// GATv2 gather: one 64-lane wave per destination node. No atomics.
// NC = 4*C channels, lane holds VEC = NC/64 contiguous channels; each head is
// a 16-lane group. Softmax max-shift skipped (logits tiny; shift-invariant).
// Edge metadata staged 64-at-a-time and broadcast via shfl.
// MODE 0: out[d] = relu(acc/den + bo [+ sl tiled across heads])     (NC wide)
// MODE 1: out[d] = relu(mean_h(acc_h/den_h) + bo + sl)              (C wide)
// ---------------------------------------------------------------------------
template <int C, int MODE>
__global__ void gat_gather(const int* __restrict__ rp, const int* __restrict__ perm,
                           const int* __restrict__ src, const float* __restrict__ ea,
                           const float* __restrict__ We, const float* __restrict__ att,
                           const float* __restrict__ xl, const float* __restrict__ xr,
                           const float* __restrict__ bo, const float* __restrict__ sl,
                           float* __restrict__ out, int n_dst) {
  constexpr int NC = 4 * C;
  constexpr int VEC = NC / 64;
  int wid = (blockIdx.x * blockDim.x + threadIdx.x) >> 6;
  int lane = threadIdx.x & 63;
  if (wid >= n_dst) return;
  int d = wid;

  float wev[VEC], atv[VEC], xrv[VEC], acc[VEC];
  if constexpr (VEC == 2) {
    *reinterpret_cast<float2*>(wev) = *reinterpret_cast<const float2*>(We + lane * VEC);
    *reinterpret_cast<float2*>(atv) = *reinterpret_cast<const float2*>(att + lane * VEC);
    *reinterpret_cast<float2*>(xrv) = *reinterpret_cast<const float2*>(xr + (size_t)d * NC + lane * VEC);
  } else {
    *reinterpret_cast<float4*>(wev) = *reinterpret_cast<const float4*>(We + lane * VEC);
    *reinterpret_cast<float4*>(atv) = *reinterpret_cast<const float4*>(att + lane * VEC);
    *reinterpret_cast<float4*>(xrv) = *reinterpret_cast<const float4*>(xr + (size_t)d * NC + lane * VEC);
  }
#pragma unroll
  for (int v = 0; v < VEC; v++) acc[v] = 0.f;
  float den = 0.f;

  int beg = rp[d], end = rp[d + 1];
  for (int i0 = beg; i0 < end; i0 += 64) {
    int cnt = min(64, end - i0);
    int s_l = 0; float ea_l = 0.f;
    if (lane < cnt) {
      int e = perm[i0 + lane];
      s_l = src[e];
      ea_l = ea[e];
    }
    for (int k = 0; k < cnt; k++) {
      int s = __shfl(s_l, k);
      float eav = __shfl(ea_l, k);
      float xlv[VEC];
      const float* xls = xl + (size_t)s * NC + lane * VEC;
      if constexpr (VEC == 2) {
        *reinterpret_cast<float2*>(xlv) = *reinterpret_cast<const float2*>(xls);
      } else {
        *reinterpret_cast<float4*>(xlv) = *reinterpret_cast<const float4*>(xls);
      }
      float p = 0.f;
#pragma unroll
      for (int v = 0; v < VEC; v++) {
        float mm = xlv[v] + xrv[v] + eav * wev[v];
        mm = mm > 0.f ? mm : 0.2f * mm;            // leaky_relu(., 0.2)
        p = fmaf(mm, atv[v], p);
      }
      p += __shfl_xor(p, 1);
      p += __shfl_xor(p, 2);
      p += __shfl_xor(p, 4);
      p += __shfl_xor(p, 8);                       // head-wide logit
      float ex = __expf(p);
      den += ex;
#pragma unroll
      for (int v = 0; v < VEC; v++) acc[v] = fmaf(ex, xlv[v], acc[v]);
    }
  }

  float inv = den > 0.f ? 1.f / den : 0.f;
  if constexpr (MODE == 0) {
#pragma unroll
    for (int v = 0; v < VEC; v++) {
      int j = lane * VEC + v;
      float val = acc[v] * inv + bo[j];
      if (sl) val += sl[(size_t)d * C + (j & (C - 1))];
      out[(size_t)d * NC + j] = val > 0.f ? val : 0.f;
    }
  } else {
#pragma unroll
    for (int v = 0; v < VEC; v++) {
      float s_ = acc[v] * inv;
      s_ += __shfl_xor(s_, 16);
      s_ += __shfl_xor(s_, 32);                    // sum over the 4 heads
      if (lane < 16) {
        int c = (lane & 15) * VEC + v;
        float val = 0.25f * s_ + bo[c] + sl[(size_t)d * C + c];
        out[(size_t)d * C + c] = val > 0.f ? val : 0.f;
      }
    }
  }
}

// ---------------------------------------------------------------------------

static inline int nblk(long long threads) { return (int)((threads + 255) / 256); }
static inline int nrow(int M, int R) { return (M + R - 1) / R; }

extern "C" void kernel_launch(void* const* d_in, const int* in_sizes, int n_in,
                              void* d_out, int out_size, void* d_ws, size_t ws_size,
                              hipStream_t stream) {
  const float* x_mrna = (const float*)d_in[0];
  const float* x_gene = (const float*)d_in[1];
  const int* sg_src = (const int*)d_in[2];
  const int* sg_dst = (const int*)d_in[3];
  const int* gs_src = (const int*)d_in[4];
  const int* gs_dst = (const int*)d_in[5];
  const float* ea_sg = (const float*)d_in[6];
  const float* ea_gs = (const float*)d_in[7];
  const float* Wl1_sg = (const float*)d_in[8];
  const float* bl1_sg = (const float*)d_in[9];
  const float* Wr1_sg = (const float*)d_in[10];
  const float* br1_sg = (const float*)d_in[11];
  const float* We1_sg = (const float*)d_in[12];
  const float* att1_sg = (const float*)d_in[13];
  const float* bo1_sg = (const float*)d_in[14];
  const float* Wl1_gs = (const float*)d_in[15];
  const float* bl1_gs = (const float*)d_in[16];
  const float* Wr1_gs = (const float*)d_in[17];
  const float* br1_gs = (const float*)d_in[18];
  const float* We1_gs = (const float*)d_in[19];
  const float* att1_gs = (const float*)d_in[20];
  const float* bo1_gs = (const float*)d_in[21];
  const float* Wl3_gs = (const float*)d_in[22];
  const float* bl3_gs = (const float*)d_in[23];
  const float* Wr3_gs = (const float*)d_in[24];
  const float* br3_gs = (const float*)d_in[25];
  const float* We3_gs = (const float*)d_in[26];
  const float* att3_gs = (const float*)d_in[27];
  const float* bo3_gs = (const float*)d_in[28];
  const float* Wsl1 = (const float*)d_in[29];
  const float* bsl1 = (const float*)d_in[30];
  const float* Wsl3 = (const float*)d_in[31];
  const float* bsl3 = (const float*)d_in[32];

  // ---- workspace arena (fp32 element offsets) ----
  // xl3 (phase D, 12.8M floats) aliases [0, 12.8M) where the dead phase-B
  // buffers xl1_gs/xl1_sg live. Gather outputs alias their own xr inputs
  // (wave d reads xr[d] before writing out[d]; no cross-wave access).
  float* ws = (float*)d_ws;
  float* xl1_gs  = ws + 0;         // [50000*128] dead after phase C
  float* xl1_sg  = ws + 6400000;   // [4000 *128] dead after phase C
  float* xl3     = ws + 0;         // [50000*256] phase D/E
  float* xr1_sg  = ws + 12800000;  // [50000*128]
  float* x1_gene = ws + 12800000;  //   gather out aliases xr1_sg
  float* xr1_gs  = ws + 19200000;  // [4000 *128]
  float* x1_mrna = ws + 19200000;  //   gather out aliases xr1_gs
  float* sl1     = ws + 19712000;  // [4000 * 32]
  float* xr3     = ws + 19840000;  // [4000 *256]
  float* sl3     = ws + 20864000;  // [4000 * 64]
  int*   ib      = (int*)(ws + 21120000);
  int* cnt_sg = ib + 0;        // [50000]  } zeroed
  int* cur_sg = ib + 50000;    // [50000]  } by one
  int* cnt_gs = ib + 100000;   // [4000]   } memset
  int* cur_gs = ib + 104000;   // [4000]   }
  int* rp_sg  = ib + 108000;   // [50001]
  int* rp_gs  = ib + 158001;   // [4001]
  int* perm_sg = ib + 162002;  // [250000]
  int* perm_gs = ib + 412002;  // [250000] -> end 662002 ints (~87.1 MB total)

  // zero CSR counters (ws is poisoned 0xAA before every timed call)
  hipMemsetAsync(cnt_sg, 0, 108000 * sizeof(int), stream);

  // ---- phase A: CSR build for both relations ----
  hist_kernel<<<nblk(NE), 256, 0, stream>>>(sg_dst, cnt_sg);
  hist_kernel<<<nblk(NE), 256, 0, stream>>>(gs_dst, cnt_gs);
  exscan<<<1, 1024, 0, stream>>>(cnt_sg, rp_sg, NG);
  exscan<<<1, 1024, 0, stream>>>(cnt_gs, rp_gs, NS);
  scatter_kernel<<<nblk(NE), 256, 0, stream>>>(sg_dst, rp_sg, cur_sg, perm_sg);
  scatter_kernel<<<nblk(NE), 256, 0, stream>>>(gs_dst, rp_gs, cur_gs, perm_gs);

  // ---- phase B: node GEMMs (layer 1) ----
  rowgemm<128><<<nrow(NS, 8), 256, 0, stream>>>(x_mrna, Wl1_sg, bl1_sg, xl1_sg, NS);
  rowgemm<128><<<nrow(NG, 8), 256, 0, stream>>>(x_gene, Wr1_sg, br1_sg, xr1_sg, NG);
  rowgemm<128><<<nrow(NG, 8), 256, 0, stream>>>(x_gene, Wl1_gs, bl1_gs, xl1_gs, NG);
  rowgemm<128><<<nrow(NS, 8), 256, 0, stream>>>(x_mrna, Wr1_gs, br1_gs, xr1_gs, NS);
  rowgemm<32><<<nrow(NS, 32), 256, 0, stream>>>(x_mrna, Wsl1, bsl1, sl1, NS);

  // ---- phase C: layer-1 gathers (fused epilogue: bias, self-loop tile, relu) ----
  gat_gather<32, 0><<<nblk((long long)NG * 64), 256, 0, stream>>>(
      rp_sg, perm_sg, sg_src, ea_sg, We1_sg, att1_sg,
      xl1_sg, xr1_sg, bo1_sg, (const float*)nullptr, x1_gene, NG);
  gat_gather<32, 0><<<nblk((long long)NS * 64), 256, 0, stream>>>(
      rp_gs, perm_gs, gs_src, ea_gs, We1_gs, att1_gs,
      xl1_gs, xr1_gs, bo1_gs, sl1, x1_mrna, NS);

  // ---- phase D: node GEMMs (layer 3) ----
  rowgemm<256><<<nrow(NG, 4), 256, 0, stream>>>(x1_gene, Wl3_gs, bl3_gs, xl3, NG);
  rowgemm<256><<<nrow(NS, 4), 256, 0, stream>>>(x1_mrna, Wr3_gs, br3_gs, xr3, NS);
  rowgemm<64><<<nrow(NS, 16), 256, 0, stream>>>(x1_mrna, Wsl3, bsl3, sl3, NS);

  // ---- phase E: layer-3 gather (fused head-mean, self-loop, relu) -> d_out ----
  gat_gather<64, 1><<<nblk((long long)NS * 64), 256, 0, stream>>>(
      rp_gs, perm_gs, gs_src, ea_gs, We3_gs, att3_gs,
      xl3, xr3, bo3_gs, sl3, (float*)d_out, NS);
}

// Round 4
// 535.420 us; speedup vs baseline: 3.5201x; 1.5091x over previous
//
#include <hip/hip_runtime.h>
#include <cstdint>
#include <cstddef>

// Problem constants (match reference)
#define NS 4000
#define NG 50000
#define NE 250000
#define DIM 128

typedef __bf16 bf16_t;
typedef bf16_t bf16x8 __attribute__((ext_vector_type(8)));
typedef float floatx4 __attribute__((ext_vector_type(4)));

// ---------------------------------------------------------------------------
// Wt[n][k] = bf16(W[k][n]); K = 128 fixed, N in {128, 256}.
// ---------------------------------------------------------------------------
__global__ void wtrans(const float* __restrict__ W, bf16_t* __restrict__ Wt, int N) {
  int idx = blockIdx.x * 256 + threadIdx.x;
  if (idx >= 128 * N) return;
  int k = idx / N, n = idx - k * N;
  Wt[n * 128 + k] = (bf16_t)W[idx];
}

// ---------------------------------------------------------------------------
// Y[M,N] = X[M,128] @ W[128,N] + b   via bf16 MFMA (fp32 X cast on the fly).
// Wt is W transposed to [N][128] bf16. No LDS. Block = 4 waves = 64 rows.
// Wave w handles rows [blk*64 + w*16, +16), all NT=N/16 col-tiles.
// A-frag: lane holds A[m=lane&15][k = kk*32 + quad*8 + j]  (16B per kk)
// B-frag: lane holds Wt[n = nt*16 + (lane&15)][k = kk*32 + quad*8 + j]
// C/D   : col = lane&15, row = quad*4 + reg   (verified gfx950 mapping)
// ---------------------------------------------------------------------------
template <int NT>
__global__ __launch_bounds__(256) void mfma_gemm(const float* __restrict__ X,
                                                 const bf16_t* __restrict__ Wt,
                                                 const float* __restrict__ B,
                                                 float* __restrict__ Y, int M) {
  constexpr int N = NT * 16;
  int wv = threadIdx.x >> 6, lane = threadIdx.x & 63;
  int m16 = lane & 15, quad = lane >> 4;
  int row0 = blockIdx.x * 64 + wv * 16;
  int arow = row0 + m16;
  const float* xp = X + (size_t)arow * DIM + quad * 8;

  bf16x8 afrag[4];
#pragma unroll
  for (int kk = 0; kk < 4; kk++) {
    float4 lo = make_float4(0.f, 0.f, 0.f, 0.f), hi = lo;
    if (arow < M) {
      lo = *reinterpret_cast<const float4*>(xp + kk * 32);
      hi = *reinterpret_cast<const float4*>(xp + kk * 32 + 4);
    }
    bf16x8 a;
    a[0] = (bf16_t)lo.x; a[1] = (bf16_t)lo.y; a[2] = (bf16_t)lo.z; a[3] = (bf16_t)lo.w;
    a[4] = (bf16_t)hi.x; a[5] = (bf16_t)hi.y; a[6] = (bf16_t)hi.z; a[7] = (bf16_t)hi.w;
    afrag[kk] = a;
  }

#pragma unroll
  for (int nt = 0; nt < NT; nt++) {
    int col = nt * 16 + m16;
    const bf16_t* bptr = Wt + (size_t)col * DIM + quad * 8;
    floatx4 acc = {0.f, 0.f, 0.f, 0.f};
#pragma unroll
    for (int kk = 0; kk < 4; kk++) {
      bf16x8 b = *reinterpret_cast<const bf16x8*>(bptr + kk * 32);
      acc = __builtin_amdgcn_mfma_f32_16x16x32_bf16(afrag[kk], b, acc, 0, 0, 0);
    }
    float bias = B[col];
    int orow = row0 + quad * 4;
#pragma unroll
    for (int r = 0; r < 4; r++)
      if (orow + r < M) Y[(size_t)(orow + r) * N + col] = acc[r] + bias;
  }
}

// ---------------------------------------------------------------------------
// Small fp32 vector GEMM (self-loop linears, N in {32, 64}).
// ---------------------------------------------------------------------------
template <int N>
__global__ __launch_bounds__(256) void rowgemm(const float* __restrict__ X,
                                               const float* __restrict__ W,
                                               const float* __restrict__ B,
                                               float* __restrict__ Y, int M) {
  constexpr int TPR = N / 4;
  constexpr int R = 256 / TPR;
  __shared__ float xs[R * DIM];
  int row0 = blockIdx.x * R;
  for (int i = threadIdx.x * 4; i < R * DIM; i += 1024) {
    int gr = row0 + (i >> 7);
    float4 v = make_float4(0.f, 0.f, 0.f, 0.f);
    if (gr < M) v = *reinterpret_cast<const float4*>(X + (size_t)gr * DIM + (i & 127));
    *reinterpret_cast<float4*>(xs + i) = v;
  }
  __syncthreads();
  int r = threadIdx.x / TPR;
  int n0 = (threadIdx.x % TPR) * 4;
  int m = row0 + r;
  if (m >= M) return;
  const float* xrow = xs + r * DIM;
  float4 acc = make_float4(0.f, 0.f, 0.f, 0.f);
#pragma unroll 8
  for (int k = 0; k < DIM; k++) {
    float xk = xrow[k];
    float4 w = *reinterpret_cast<const float4*>(W + (size_t)k * N + n0);
    acc.x = fmaf(xk, w.x, acc.x);
    acc.y = fmaf(xk, w.y, acc.y);
    acc.z = fmaf(xk, w.z, acc.z);
    acc.w = fmaf(xk, w.w, acc.w);
  }
  float4 b = *reinterpret_cast<const float4*>(B + n0);
  acc.x += b.x; acc.y += b.y; acc.z += b.z; acc.w += b.w;
  *reinterpret_cast<float4*>(Y + (size_t)m * N + n0) = acc;
}

// ---------------------------------------------------------------------------
// CSR build: histogram -> exclusive scan -> permutation scatter
// ---------------------------------------------------------------------------
__global__ void hist_kernel(const int* __restrict__ dst, int* __restrict__ cnt) {
  int e = blockIdx.x * blockDim.x + threadIdx.x;
  if (e < NE) atomicAdd(cnt + dst[e], 1);
}

__global__ __launch_bounds__(1024) void exscan(const int* __restrict__ cnt,
                                               int* __restrict__ rp, int n) {
  __shared__ int wsum[16];
  __shared__ int carry_s;
  int lane = threadIdx.x & 63;
  int w = threadIdx.x >> 6;
  if (threadIdx.x == 0) carry_s = 0;
  __syncthreads();
  for (int base = 0; base < n; base += 1024) {
    int i = base + threadIdx.x;
    int v = (i < n) ? cnt[i] : 0;
    int x = v;
#pragma unroll
    for (int off = 1; off < 64; off <<= 1) {
      int y = __shfl_up(x, off);
      if (lane >= off) x += y;
    }
    if (lane == 63) wsum[w] = x;
    __syncthreads();
    if (w == 0 && lane < 16) {
      int s = wsum[lane];
#pragma unroll
      for (int off = 1; off < 16; off <<= 1) {
        int y = __shfl_up(s, off);
        if (lane >= off) s += y;
      }
      wsum[lane] = s;
    }
    __syncthreads();
    int wpre = (w == 0) ? 0 : wsum[w - 1];
    int incl = x + wpre;
    int carry = carry_s;
    if (i < n) rp[i] = carry + incl - v;
    int total = wsum[15];
    __syncthreads();
    if (threadIdx.x == 0) carry_s = carry + total;
    __syncthreads();
  }
  if (threadIdx.x == 0) rp[n] = carry_s;
}

__global__ void scatter_kernel(const int* __restrict__ dst, const int* __restrict__ rp,
                               int* __restrict__ cur, int* __restrict__ perm) {
  int e = blockIdx.x * blockDim.x + threadIdx.x;
  if (e >= NE) return;
  int d = dst[e];
  int pos = atomicAdd(cur + d, 1);
  perm[rp[d] + pos] = e;
}

// ---------------------------------------------------------------------------
// GATv2 gather: one 64-lane wave per destination node. No atomics.
// ---------------------------------------------------------------------------
template <int C, int MODE>
__global__ void gat_gather(const int* __restrict__ rp, const int* __restrict__ perm,
                           const int* __restrict__ src, const float* __restrict__ ea,
                           const float* __restrict__ We, const float* __restrict__ att,
                           const float* __restrict__ xl, const float* __restrict__ xr,
                           const float* __restrict__ bo, const float* __restrict__ sl,
                           float* __restrict__ out, int n_dst) {
  constexpr int NC = 4 * C;
  constexpr int VEC = NC / 64;
  int wid = (blockIdx.x * blockDim.x + threadIdx.x) >> 6;
  int lane = threadIdx.x & 63;
  if (wid >= n_dst) return;
  int d = wid;

  float wev[VEC], atv[VEC], xrv[VEC], acc[VEC];
  if constexpr (VEC == 2) {
    *reinterpret_cast<float2*>(wev) = *reinterpret_cast<const float2*>(We + lane * VEC);
    *reinterpret_cast<float2*>(atv) = *reinterpret_cast<const float2*>(att + lane * VEC);
    *reinterpret_cast<float2*>(xrv) = *reinterpret_cast<const float2*>(xr + (size_t)d * NC + lane * VEC);
  } else {
    *reinterpret_cast<float4*>(wev) = *reinterpret_cast<const float4*>(We + lane * VEC);
    *reinterpret_cast<float4*>(atv) = *reinterpret_cast<const float4*>(att + lane * VEC);
    *reinterpret_cast<float4*>(xrv) = *reinterpret_cast<const float4*>(xr + (size_t)d * NC + lane * VEC);
  }
#pragma unroll
  for (int v = 0; v < VEC; v++) acc[v] = 0.f;
  float den = 0.f;

  int beg = rp[d], end = rp[d + 1];
  for (int i0 = beg; i0 < end; i0 += 64) {
    int cnt = min(64, end - i0);
    int s_l = 0; float ea_l = 0.f;
    if (lane < cnt) {
      int e = perm[i0 + lane];
      s_l = src[e];
      ea_l = ea[e];
    }
    for (int k = 0; k < cnt; k++) {
      int s = __shfl(s_l, k);
      float eav = __shfl(ea_l, k);
      float xlv[VEC];
      const float* xls = xl + (size_t)s * NC + lane * VEC;
      if constexpr (VEC == 2) {
        *reinterpret_cast<float2*>(xlv) = *reinterpret_cast<const float2*>(xls);
      } else {
        *reinterpret_cast<float4*>(xlv) = *reinterpret_cast<const float4*>(xls);
      }
      float p = 0.f;
#pragma unroll
      for (int v = 0; v < VEC; v++) {
        float mm = xlv[v] + xrv[v] + eav * wev[v];
        mm = mm > 0.f ? mm : 0.2f * mm;            // leaky_relu(., 0.2)
        p = fmaf(mm, atv[v], p);
      }
      p += __shfl_xor(p, 1);
      p += __shfl_xor(p, 2);
      p += __shfl_xor(p, 4);
      p += __shfl_xor(p, 8);                       // head-wide logit
      float ex = __expf(p);
      den += ex;
#pragma unroll
      for (int v = 0; v < VEC; v++) acc[v] = fmaf(ex, xlv[v], acc[v]);
    }
  }

  float inv = den > 0.f ? 1.f / den : 0.f;
  if constexpr (MODE == 0) {
#pragma unroll
    for (int v = 0; v < VEC; v++) {
      int j = lane * VEC + v;
      float val = acc[v] * inv + bo[j];
      if (sl) val += sl[(size_t)d * C + (j & (C - 1))];
      out[(size_t)d * NC + j] = val > 0.f ? val : 0.f;
    }
  } else {
#pragma unroll
    for (int v = 0; v < VEC; v++) {
      float s_ = acc[v] * inv;
      s_ += __shfl_xor(s_, 16);
      s_ += __shfl_xor(s_, 32);                    // sum over the 4 heads
      if (lane < 16) {
        int c = (lane & 15) * VEC + v;
        float val = 0.25f * s_ + bo[c] + sl[(size_t)d * C + c];
        out[(size_t)d * C + c] = val > 0.f ? val : 0.f;
      }
    }
  }
}

// ---------------------------------------------------------------------------

static inline int nblk(long long threads) { return (int)((threads + 255) / 256); }
static inline int nrow(int M, int R) { return (M + R - 1) / R; }

extern "C" void kernel_launch(void* const* d_in, const int* in_sizes, int n_in,
                              void* d_out, int out_size, void* d_ws, size_t ws_size,
                              hipStream_t stream) {
  const float* x_mrna = (const float*)d_in[0];
  const float* x_gene = (const float*)d_in[1];
  const int* sg_src = (const int*)d_in[2];
  const int* sg_dst = (const int*)d_in[3];
  const int* gs_src = (const int*)d_in[4];
  const int* gs_dst = (const int*)d_in[5];
  const float* ea_sg = (const float*)d_in[6];
  const float* ea_gs = (const float*)d_in[7];
  const float* Wl1_sg = (const float*)d_in[8];
  const float* bl1_sg = (const float*)d_in[9];
  const float* Wr1_sg = (const float*)d_in[10];
  const float* br1_sg = (const float*)d_in[11];
  const float* We1_sg = (const float*)d_in[12];
  const float* att1_sg = (const float*)d_in[13];
  const float* bo1_sg = (const float*)d_in[14];
  const float* Wl1_gs = (const float*)d_in[15];
  const float* bl1_gs = (const float*)d_in[16];
  const float* Wr1_gs = (const float*)d_in[17];
  const float* br1_gs = (const float*)d_in[18];
  const float* We1_gs = (const float*)d_in[19];
  const float* att1_gs = (const float*)d_in[20];
  const float* bo1_gs = (const float*)d_in[21];
  const float* Wl3_gs = (const float*)d_in[22];
  const float* bl3_gs = (const float*)d_in[23];
  const float* Wr3_gs = (const float*)d_in[24];
  const float* br3_gs = (const float*)d_in[25];
  const float* We3_gs = (const float*)d_in[26];
  const float* att3_gs = (const float*)d_in[27];
  const float* bo3_gs = (const float*)d_in[28];
  const float* Wsl1 = (const float*)d_in[29];
  const float* bsl1 = (const float*)d_in[30];
  const float* Wsl3 = (const float*)d_in[31];
  const float* bsl3 = (const float*)d_in[32];

  // ---- workspace arena (fp32 element offsets) ----
  float* ws = (float*)d_ws;
  float* xl1_gs  = ws + 0;         // [50000*128] dead after phase C
  float* xl1_sg  = ws + 6400000;   // [4000 *128] dead after phase C
  float* xl3     = ws + 0;         // [50000*256] phase D/E (aliases the above)
  float* xr1_sg  = ws + 12800000;  // [50000*128]
  float* x1_gene = ws + 12800000;  //   gather out aliases xr1_sg
  float* xr1_gs  = ws + 19200000;  // [4000 *128]
  float* x1_mrna = ws + 19200000;  //   gather out aliases xr1_gs
  float* sl1     = ws + 19712000;  // [4000 * 32]
  float* xr3     = ws + 19840000;  // [4000 *256]
  float* sl3     = ws + 20864000;  // [4000 * 64]
  int*   ib      = (int*)(ws + 21120000);
  int* cnt_sg = ib + 0;        // [50000]  } zeroed by one memset;
  int* cur_sg = ib + 50000;    // [50000]  } dead after phase A ->
  int* cnt_gs = ib + 100000;   // [4000]   } reused for bf16 Wt buffers
  int* cur_gs = ib + 104000;   // [4000]   }
  int* rp_sg  = ib + 108000;   // [50001]
  int* rp_gs  = ib + 158001;   // [4001]
  int* perm_sg = ib + 162002;  // [250000]
  int* perm_gs = ib + 412002;  // [250000] -> end 662002 ints (~87.1 MB total)

  // bf16 transposed weights overlay the dead cnt/cur region (400 KB avail,
  // need 131072*2 = 256 KB; 16B-aligned since 21120000*4 % 16 == 0)
  bf16_t* wtb = (bf16_t*)cnt_sg;
  bf16_t* wt_l1sg = wtb + 0;      // [128*128]
  bf16_t* wt_r1sg = wtb + 16384;  // [128*128]
  bf16_t* wt_l1gs = wtb + 32768;  // [128*128]
  bf16_t* wt_r1gs = wtb + 49152;  // [128*128]
  bf16_t* wt_l3   = wtb + 65536;  // [256*128]
  bf16_t* wt_r3   = wtb + 98304;  // [256*128]

  // zero CSR counters (ws is poisoned 0xAA before every timed call)
  hipMemsetAsync(cnt_sg, 0, 108000 * sizeof(int), stream);

  // ---- phase A: CSR build for both relations ----
  hist_kernel<<<nblk(NE), 256, 0, stream>>>(sg_dst, cnt_sg);
  hist_kernel<<<nblk(NE), 256, 0, stream>>>(gs_dst, cnt_gs);
  exscan<<<1, 1024, 0, stream>>>(cnt_sg, rp_sg, NG);
  exscan<<<1, 1024, 0, stream>>>(cnt_gs, rp_gs, NS);
  scatter_kernel<<<nblk(NE), 256, 0, stream>>>(sg_dst, rp_sg, cur_sg, perm_sg);
  scatter_kernel<<<nblk(NE), 256, 0, stream>>>(gs_dst, rp_gs, cur_gs, perm_gs);

  // ---- phase A2: weight transpose + bf16 cast (cnt/cur now dead) ----
  wtrans<<<64, 256, 0, stream>>>(Wl1_sg, wt_l1sg, 128);
  wtrans<<<64, 256, 0, stream>>>(Wr1_sg, wt_r1sg, 128);
  wtrans<<<64, 256, 0, stream>>>(Wl1_gs, wt_l1gs, 128);
  wtrans<<<64, 256, 0, stream>>>(Wr1_gs, wt_r1gs, 128);
  wtrans<<<128, 256, 0, stream>>>(Wl3_gs, wt_l3, 256);
  wtrans<<<128, 256, 0, stream>>>(Wr3_gs, wt_r3, 256);

  // ---- phase B: node GEMMs (layer 1), bf16 MFMA ----
  mfma_gemm<8><<<nrow(NS, 64), 256, 0, stream>>>(x_mrna, wt_l1sg, bl1_sg, xl1_sg, NS);
  mfma_gemm<8><<<nrow(NG, 64), 256, 0, stream>>>(x_gene, wt_r1sg, br1_sg, xr1_sg, NG);
  mfma_gemm<8><<<nrow(NG, 64), 256, 0, stream>>>(x_gene, wt_l1gs, bl1_gs, xl1_gs, NG);
  mfma_gemm<8><<<nrow(NS, 64), 256, 0, stream>>>(x_mrna, wt_r1gs, br1_gs, xr1_gs, NS);
  rowgemm<32><<<nrow(NS, 32), 256, 0, stream>>>(x_mrna, Wsl1, bsl1, sl1, NS);

  // ---- phase C: layer-1 gathers (fused epilogue: bias, self-loop tile, relu) ----
  gat_gather<32, 0><<<nblk((long long)NG * 64), 256, 0, stream>>>(
      rp_sg, perm_sg, sg_src, ea_sg, We1_sg, att1_sg,
      xl1_sg, xr1_sg, bo1_sg, (const float*)nullptr, x1_gene, NG);
  gat_gather<32, 0><<<nblk((long long)NS * 64), 256, 0, stream>>>(
      rp_gs, perm_gs, gs_src, ea_gs, We1_gs, att1_gs,
      xl1_gs, xr1_gs, bo1_gs, sl1, x1_mrna, NS);

  // ---- phase D: node GEMMs (layer 3), bf16 MFMA ----
  mfma_gemm<16><<<nrow(NG, 64), 256, 0, stream>>>(x1_gene, wt_l3, bl3_gs, xl3, NG);
  mfma_gemm<16><<<nrow(NS, 64), 256, 0, stream>>>(x1_mrna, wt_r3, br3_gs, xr3, NS);
  rowgemm<64><<<nrow(NS, 16), 256, 0, stream>>>(x1_mrna, Wsl3, bsl3, sl3, NS);

  // ---- phase E: layer-3 gather (fused head-mean, self-loop, relu) -> d_out ----
  gat_gather<64, 1><<<nblk((long long)NS * 64), 256, 0, stream>>>(
      rp_gs, perm_gs, gs_src, ea_gs, We3_gs, att3_gs,
      xl3, xr3, bo3_gs, sl3, (float*)d_out, NS);
}

// Round 5
// 435.348 us; speedup vs baseline: 4.3293x; 1.2299x over previous
//
#include <hip/hip_runtime.h>
#include <cstdint>
#include <cstddef>

// Problem constants (match reference)
#define NS 4000
#define NG 50000
#define NE 250000
#define DIM 128
#define NDST_TOT (NG + NS)          // 54000 combined CSR rows (sg then gs)

typedef __bf16 bf16_t;
typedef bf16_t bf16x8 __attribute__((ext_vector_type(8)));
typedef float floatx4 __attribute__((ext_vector_type(4)));

template <int V> struct BV {};
template <> struct BV<2> { typedef bf16_t T __attribute__((ext_vector_type(2))); };
template <> struct BV<4> { typedef bf16_t T __attribute__((ext_vector_type(4))); };

// ---------------------------------------------------------------------------
// Wt[n][k] = bf16(W[k][n]); K = 128 fixed, N in {128, 256}.
// ---------------------------------------------------------------------------
__global__ void wtrans(const float* __restrict__ W, bf16_t* __restrict__ Wt, int N) {
  int idx = blockIdx.x * 256 + threadIdx.x;
  if (idx >= 128 * N) return;
  int k = idx / N, n = idx - k * N;
  Wt[n * 128 + k] = (bf16_t)W[idx];
}

// ---------------------------------------------------------------------------
// Y[M,N] = X[M,128] @ W[128,N] + b  via bf16 MFMA. TOUT in {float, bf16_t}.
// ---------------------------------------------------------------------------
template <int NT, typename TOUT>
__global__ __launch_bounds__(256) void mfma_gemm(const float* __restrict__ X,
                                                 const bf16_t* __restrict__ Wt,
                                                 const float* __restrict__ B,
                                                 TOUT* __restrict__ Y, int M) {
  constexpr int N = NT * 16;
  int wv = threadIdx.x >> 6, lane = threadIdx.x & 63;
  int m16 = lane & 15, quad = lane >> 4;
  int row0 = blockIdx.x * 64 + wv * 16;
  int arow = row0 + m16;
  const float* xp = X + (size_t)arow * DIM + quad * 8;

  bf16x8 afrag[4];
#pragma unroll
  for (int kk = 0; kk < 4; kk++) {
    float4 lo = make_float4(0.f, 0.f, 0.f, 0.f), hi = lo;
    if (arow < M) {
      lo = *reinterpret_cast<const float4*>(xp + kk * 32);
      hi = *reinterpret_cast<const float4*>(xp + kk * 32 + 4);
    }
    bf16x8 a;
    a[0] = (bf16_t)lo.x; a[1] = (bf16_t)lo.y; a[2] = (bf16_t)lo.z; a[3] = (bf16_t)lo.w;
    a[4] = (bf16_t)hi.x; a[5] = (bf16_t)hi.y; a[6] = (bf16_t)hi.z; a[7] = (bf16_t)hi.w;
    afrag[kk] = a;
  }

#pragma unroll
  for (int nt = 0; nt < NT; nt++) {
    int col = nt * 16 + m16;
    const bf16_t* bptr = Wt + (size_t)col * DIM + quad * 8;
    floatx4 acc = {0.f, 0.f, 0.f, 0.f};
#pragma unroll
    for (int kk = 0; kk < 4; kk++) {
      bf16x8 b = *reinterpret_cast<const bf16x8*>(bptr + kk * 32);
      acc = __builtin_amdgcn_mfma_f32_16x16x32_bf16(afrag[kk], b, acc, 0, 0, 0);
    }
    float bias = B[col];
    int orow = row0 + quad * 4;
#pragma unroll
    for (int r = 0; r < 4; r++)
      if (orow + r < M) Y[(size_t)(orow + r) * N + col] = (TOUT)(acc[r] + bias);
  }
}

// ---------------------------------------------------------------------------
// Small fp32 vector GEMM (self-loop linears, N in {32, 64}).
// ---------------------------------------------------------------------------
template <int N>
__global__ __launch_bounds__(256) void rowgemm(const float* __restrict__ X,
                                               const float* __restrict__ W,
                                               const float* __restrict__ B,
                                               float* __restrict__ Y, int M) {
  constexpr int TPR = N / 4;
  constexpr int R = 256 / TPR;
  __shared__ float xs[R * DIM];
  int row0 = blockIdx.x * R;
  for (int i = threadIdx.x * 4; i < R * DIM; i += 1024) {
    int gr = row0 + (i >> 7);
    float4 v = make_float4(0.f, 0.f, 0.f, 0.f);
    if (gr < M) v = *reinterpret_cast<const float4*>(X + (size_t)gr * DIM + (i & 127));
    *reinterpret_cast<float4*>(xs + i) = v;
  }
  __syncthreads();
  int r = threadIdx.x / TPR;
  int n0 = (threadIdx.x % TPR) * 4;
  int m = row0 + r;
  if (m >= M) return;
  const float* xrow = xs + r * DIM;
  float4 acc = make_float4(0.f, 0.f, 0.f, 0.f);
#pragma unroll 8
  for (int k = 0; k < DIM; k++) {
    float xk = xrow[k];
    float4 w = *reinterpret_cast<const float4*>(W + (size_t)k * N + n0);
    acc.x = fmaf(xk, w.x, acc.x);
    acc.y = fmaf(xk, w.y, acc.y);
    acc.z = fmaf(xk, w.z, acc.z);
    acc.w = fmaf(xk, w.w, acc.w);
  }
  float4 b = *reinterpret_cast<const float4*>(B + n0);
  acc.x += b.x; acc.y += b.y; acc.z += b.z; acc.w += b.w;
  *reinterpret_cast<float4*>(Y + (size_t)m * N + n0) = acc;
}

// ---------------------------------------------------------------------------
// Combined CSR build (sg rows [0,NG), gs rows [NG,NG+NS)); one perm array.
// Total sg edges = NE statically, so gs rp values index perm at +NE.
// ---------------------------------------------------------------------------
__global__ void hist2(const int* __restrict__ sgd, const int* __restrict__ gsd,
                      int* __restrict__ cnt) {
  int e = blockIdx.x * 256 + threadIdx.x;
  if (e >= NE) return;
  atomicAdd(cnt + sgd[e], 1);
  atomicAdd(cnt + NG + gsd[e], 1);
}

// 3-phase parallel exclusive scan over n=54000 (53 chunks of 1024)
__global__ __launch_bounds__(1024) void scan1(const int* __restrict__ cnt,
                                              int* __restrict__ rp,
                                              int* __restrict__ csum, int n) {
  __shared__ int wsum[16];
  int i = blockIdx.x * 1024 + threadIdx.x;
  int lane = threadIdx.x & 63, w = threadIdx.x >> 6;
  int v = (i < n) ? cnt[i] : 0;
  int x = v;
#pragma unroll
  for (int off = 1; off < 64; off <<= 1) {
    int y = __shfl_up(x, off);
    if (lane >= off) x += y;
  }
  if (lane == 63) wsum[w] = x;
  __syncthreads();
  if (w == 0 && lane < 16) {
    int s = wsum[lane];
#pragma unroll
    for (int off = 1; off < 16; off <<= 1) {
      int y = __shfl_up(s, off);
      if (lane >= off) s += y;
    }
    wsum[lane] = s;
  }
  __syncthreads();
  int incl = x + (w ? wsum[w - 1] : 0);
  if (i < n) rp[i] = incl - v;                 // exclusive within block
  if (threadIdx.x == 1023) csum[blockIdx.x] = incl;
}

__global__ void scan2(int* __restrict__ csum, int nb) {   // 1 wave, nb <= 64
  int lane = threadIdx.x;
  int v = (lane < nb) ? csum[lane] : 0;
  int x = v;
#pragma unroll
  for (int off = 1; off < 64; off <<= 1) {
    int y = __shfl_up(x, off);
    if (lane >= off) x += y;
  }
  if (lane < nb) csum[lane] = x - v;           // exclusive
}

__global__ __launch_bounds__(1024) void scan3(int* __restrict__ rp,
                                              const int* __restrict__ csum, int n) {
  int i = blockIdx.x * 1024 + threadIdx.x;
  if (i < n) rp[i] += csum[blockIdx.x];
  if (i == 0) rp[n] = 2 * NE;                  // static total sentinel
}

__global__ void scatter_kernel(const int* __restrict__ dst, const int* __restrict__ rp,
                               int* __restrict__ cur, int* __restrict__ perm) {
  int e = blockIdx.x * blockDim.x + threadIdx.x;
  if (e >= NE) return;
  int d = dst[e];
  int pos = atomicAdd(cur + d, 1);
  perm[rp[d] + pos] = e;
}

// ---------------------------------------------------------------------------
// GATv2 gather: one 64-lane wave per destination node; xl in bf16.
// Inner loop batches 4 edges: all 4 row-gathers issued before compute (MLP=4);
// tail edges repeat edge k0 with ex masked to 0.
// ---------------------------------------------------------------------------
template <int C, int MODE>
__global__ void gat_gather(const int* __restrict__ rp, const int* __restrict__ perm,
                           const int* __restrict__ src, const float* __restrict__ ea,
                           const float* __restrict__ We, const float* __restrict__ att,
                           const bf16_t* __restrict__ xl, const float* __restrict__ xr,
                           const float* __restrict__ bo, const float* __restrict__ sl,
                           float* __restrict__ out, int n_dst) {
  constexpr int NC = 4 * C;
  constexpr int VEC = NC / 64;
  typedef typename BV<VEC>::T bvec;
  int wid = (blockIdx.x * blockDim.x + threadIdx.x) >> 6;
  int lane = threadIdx.x & 63;
  if (wid >= n_dst) return;
  int d = wid;

  float wev[VEC], atv[VEC], xrv[VEC], acc[VEC];
  if constexpr (VEC == 2) {
    *reinterpret_cast<float2*>(wev) = *reinterpret_cast<const float2*>(We + lane * VEC);
    *reinterpret_cast<float2*>(atv) = *reinterpret_cast<const float2*>(att + lane * VEC);
    *reinterpret_cast<float2*>(xrv) = *reinterpret_cast<const float2*>(xr + (size_t)d * NC + lane * VEC);
  } else {
    *reinterpret_cast<float4*>(wev) = *reinterpret_cast<const float4*>(We + lane * VEC);
    *reinterpret_cast<float4*>(atv) = *reinterpret_cast<const float4*>(att + lane * VEC);
    *reinterpret_cast<float4*>(xrv) = *reinterpret_cast<const float4*>(xr + (size_t)d * NC + lane * VEC);
  }
#pragma unroll
  for (int v = 0; v < VEC; v++) acc[v] = 0.f;
  float den = 0.f;

  int beg = rp[d], end = rp[d + 1];
  for (int i0 = beg; i0 < end; i0 += 64) {
    int cnt = min(64, end - i0);
    int s_l = 0; float ea_l = 0.f;
    if (lane < cnt) {
      int e = perm[i0 + lane];
      s_l = src[e];
      ea_l = ea[e];
    }
    for (int k0 = 0; k0 < cnt; k0 += 4) {
      int s4[4]; float ea4[4];
      bvec raw[4];
#pragma unroll
      for (int g = 0; g < 4; g++) {
        int kk = (k0 + g < cnt) ? k0 + g : k0;
        s4[g] = __shfl(s_l, kk);
        ea4[g] = __shfl(ea_l, kk);
      }
#pragma unroll
      for (int g = 0; g < 4; g++)
        raw[g] = *reinterpret_cast<const bvec*>(xl + (size_t)s4[g] * NC + lane * VEC);
#pragma unroll
      for (int g = 0; g < 4; g++) {
        float xf[VEC];
        float p = 0.f;
#pragma unroll
        for (int v = 0; v < VEC; v++) {
          xf[v] = (float)raw[g][v];
          float mm = xf[v] + xrv[v] + ea4[g] * wev[v];
          mm = mm > 0.f ? mm : 0.2f * mm;        // leaky_relu(., 0.2)
          p = fmaf(mm, atv[v], p);
        }
        p += __shfl_xor(p, 1);
        p += __shfl_xor(p, 2);
        p += __shfl_xor(p, 4);
        p += __shfl_xor(p, 8);                   // head-wide logit
        float ex = __expf(p);
        if (k0 + g >= cnt) ex = 0.f;             // mask tail repeats
        den += ex;
#pragma unroll
        for (int v = 0; v < VEC; v++) acc[v] = fmaf(ex, xf[v], acc[v]);
      }
    }
  }

  float inv = den > 0.f ? 1.f / den : 0.f;
  if constexpr (MODE == 0) {
#pragma unroll
    for (int v = 0; v < VEC; v++) {
      int j = lane * VEC + v;
      float val = acc[v] * inv + bo[j];
      if (sl) val += sl[(size_t)d * C + (j & (C - 1))];
      out[(size_t)d * NC + j] = val > 0.f ? val : 0.f;
    }
  } else {
#pragma unroll
    for (int v = 0; v < VEC; v++) {
      float s_ = acc[v] * inv;
      s_ += __shfl_xor(s_, 16);
      s_ += __shfl_xor(s_, 32);                  // sum over the 4 heads
      if (lane < 16) {
        int c = (lane & 15) * VEC + v;
        float val = 0.25f * s_ + bo[c] + sl[(size_t)d * C + c];
        out[(size_t)d * C + c] = val > 0.f ? val : 0.f;
      }
    }
  }
}

// ---------------------------------------------------------------------------

static inline int nblk(long long threads) { return (int)((threads + 255) / 256); }
static inline int nrow(int M, int R) { return (M + R - 1) / R; }

extern "C" void kernel_launch(void* const* d_in, const int* in_sizes, int n_in,
                              void* d_out, int out_size, void* d_ws, size_t ws_size,
                              hipStream_t stream) {
  const float* x_mrna = (const float*)d_in[0];
  const float* x_gene = (const float*)d_in[1];
  const int* sg_src = (const int*)d_in[2];
  const int* sg_dst = (const int*)d_in[3];
  const int* gs_src = (const int*)d_in[4];
  const int* gs_dst = (const int*)d_in[5];
  const float* ea_sg = (const float*)d_in[6];
  const float* ea_gs = (const float*)d_in[7];
  const float* Wl1_sg = (const float*)d_in[8];
  const float* bl1_sg = (const float*)d_in[9];
  const float* Wr1_sg = (const float*)d_in[10];
  const float* br1_sg = (const float*)d_in[11];
  const float* We1_sg = (const float*)d_in[12];
  const float* att1_sg = (const float*)d_in[13];
  const float* bo1_sg = (const float*)d_in[14];
  const float* Wl1_gs = (const float*)d_in[15];
  const float* bl1_gs = (const float*)d_in[16];
  const float* Wr1_gs = (const float*)d_in[17];
  const float* br1_gs = (const float*)d_in[18];
  const float* We1_gs = (const float*)d_in[19];
  const float* att1_gs = (const float*)d_in[20];
  const float* bo1_gs = (const float*)d_in[21];
  const float* Wl3_gs = (const float*)d_in[22];
  const float* bl3_gs = (const float*)d_in[23];
  const float* Wr3_gs = (const float*)d_in[24];
  const float* br3_gs = (const float*)d_in[25];
  const float* We3_gs = (const float*)d_in[26];
  const float* att3_gs = (const float*)d_in[27];
  const float* bo3_gs = (const float*)d_in[28];
  const float* Wsl1 = (const float*)d_in[29];
  const float* bsl1 = (const float*)d_in[30];
  const float* Wsl3 = (const float*)d_in[31];
  const float* bsl3 = (const float*)d_in[32];

  // ---- workspace arena (fp32 element offsets) ----
  // bf16 xl buffers; xl3 aliases the whole dead xl1 region after phase C.
  float* ws = (float*)d_ws;
  bf16_t* xl1_gs = (bf16_t*)(ws + 0);        // bf16[50000*128] -> 3.2M floats
  bf16_t* xl1_sg = (bf16_t*)(ws + 3200000);  // bf16[4000*128]  -> 0.256M floats
  bf16_t* xl3    = (bf16_t*)(ws + 0);        // bf16[50000*256] -> 6.4M floats (aliases)
  float* xr1_sg  = ws + 6400000;   // [50000*128]; x1_gene gather-out aliases
  float* x1_gene = ws + 6400000;
  float* xr1_gs  = ws + 12800000;  // [4000*128]; x1_mrna gather-out aliases
  float* x1_mrna = ws + 12800000;
  float* sl1     = ws + 13312000;  // [4000*32]
  float* xr3     = ws + 13440000;  // [4000*256]
  float* sl3     = ws + 14464000;  // [4000*64]
  int*   ib      = (int*)(ws + 14720000);
  int* cnt  = ib + 0;              // [54000] } zeroed by one memset; dead after
  int* cur  = ib + 54000;          // [54000] } phase A -> overlaid by bf16 Wt
  int* rpc  = ib + 108000;         // [54001] combined row pointers
  int* csum = ib + 162001;         // [64]    scan chunk sums
  int* perm = ib + 162065;         // [500000] combined permutation
  // end: 662065 ints  (~61.5 MB total ws)

  // bf16 transposed weights overlay dead cnt/cur (432 KB avail, need 256 KB)
  bf16_t* wtb = (bf16_t*)cnt;
  bf16_t* wt_l1sg = wtb + 0;
  bf16_t* wt_r1sg = wtb + 16384;
  bf16_t* wt_l1gs = wtb + 32768;
  bf16_t* wt_r1gs = wtb + 49152;
  bf16_t* wt_l3   = wtb + 65536;   // [256*128]
  bf16_t* wt_r3   = wtb + 98304;   // [256*128]

  // zero CSR counters (ws is poisoned 0xAA before every timed call)
  hipMemsetAsync(cnt, 0, 108000 * sizeof(int), stream);

  // ---- phase A: combined CSR build ----
  hist2<<<nblk(NE), 256, 0, stream>>>(sg_dst, gs_dst, cnt);
  int nchunks = (NDST_TOT + 1023) / 1024;            // 53
  scan1<<<nchunks, 1024, 0, stream>>>(cnt, rpc, csum, NDST_TOT);
  scan2<<<1, 64, 0, stream>>>(csum, nchunks);
  scan3<<<nchunks, 1024, 0, stream>>>(rpc, csum, NDST_TOT);
  scatter_kernel<<<nblk(NE), 256, 0, stream>>>(sg_dst, rpc, cur, perm);
  scatter_kernel<<<nblk(NE), 256, 0, stream>>>(gs_dst, rpc + NG, cur + NG, perm);

  // ---- phase A2: weight transpose + bf16 cast (cnt/cur now dead) ----
  wtrans<<<64, 256, 0, stream>>>(Wl1_sg, wt_l1sg, 128);
  wtrans<<<64, 256, 0, stream>>>(Wr1_sg, wt_r1sg, 128);
  wtrans<<<64, 256, 0, stream>>>(Wl1_gs, wt_l1gs, 128);
  wtrans<<<64, 256, 0, stream>>>(Wr1_gs, wt_r1gs, 128);
  wtrans<<<128, 256, 0, stream>>>(Wl3_gs, wt_l3, 256);
  wtrans<<<128, 256, 0, stream>>>(Wr3_gs, wt_r3, 256);

  // ---- phase B: node GEMMs (layer 1), bf16 MFMA; xl outputs in bf16 ----
  mfma_gemm<8, bf16_t><<<nrow(NS, 64), 256, 0, stream>>>(x_mrna, wt_l1sg, bl1_sg, xl1_sg, NS);
  mfma_gemm<8, float><<<nrow(NG, 64), 256, 0, stream>>>(x_gene, wt_r1sg, br1_sg, xr1_sg, NG);
  mfma_gemm<8, bf16_t><<<nrow(NG, 64), 256, 0, stream>>>(x_gene, wt_l1gs, bl1_gs, xl1_gs, NG);
  mfma_gemm<8, float><<<nrow(NS, 64), 256, 0, stream>>>(x_mrna, wt_r1gs, br1_gs, xr1_gs, NS);
  rowgemm<32><<<nrow(NS, 32), 256, 0, stream>>>(x_mrna, Wsl1, bsl1, sl1, NS);

  // ---- phase C: layer-1 gathers (fused bias/self-loop/relu epilogue) ----
  gat_gather<32, 0><<<nblk((long long)NG * 64), 256, 0, stream>>>(
      rpc, perm, sg_src, ea_sg, We1_sg, att1_sg,
      xl1_sg, xr1_sg, bo1_sg, (const float*)nullptr, x1_gene, NG);
  gat_gather<32, 0><<<nblk((long long)NS * 64), 256, 0, stream>>>(
      rpc + NG, perm, gs_src, ea_gs, We1_gs, att1_gs,
      xl1_gs, xr1_gs, bo1_gs, sl1, x1_mrna, NS);

  // ---- phase D: node GEMMs (layer 3) ----
  mfma_gemm<16, bf16_t><<<nrow(NG, 64), 256, 0, stream>>>(x1_gene, wt_l3, bl3_gs, xl3, NG);
  mfma_gemm<16, float><<<nrow(NS, 64), 256, 0, stream>>>(x1_mrna, wt_r3, br3_gs, xr3, NS);
  rowgemm<64><<<nrow(NS, 16), 256, 0, stream>>>(x1_mrna, Wsl3, bsl3, sl3, NS);

  // ---- phase E: layer-3 gather (fused head-mean/self-loop/relu) -> d_out ----
  gat_gather<64, 1><<<nblk((long long)NS * 64), 256, 0, stream>>>(
      rpc + NG, perm, gs_src, ea_gs, We3_gs, att3_gs,
      xl3, xr3, bo3_gs, sl3, (float*)d_out, NS);
}

// Round 6
// 409.639 us; speedup vs baseline: 4.6010x; 1.0628x over previous
//
#include <hip/hip_runtime.h>
#include <cstdint>
#include <cstddef>

// Problem constants (match reference)
#define NS 4000
#define NG 50000
#define NE 250000
#define DIM 128
#define NDST_TOT (NG + NS)          // 54000 combined CSR rows (sg then gs)

typedef __bf16 bf16_t;
typedef bf16_t bf16x8 __attribute__((ext_vector_type(8)));
typedef float floatx4 __attribute__((ext_vector_type(4)));

template <int V> struct BV {};
template <> struct BV<2> { typedef bf16_t T __attribute__((ext_vector_type(2))); };
template <> struct BV<4> { typedef bf16_t T __attribute__((ext_vector_type(4))); };

// ---------------------------------------------------------------------------
// Fused weight transpose+cast for all 6 matrices: Wt[n][k] = bf16(W[k][n]).
// ---------------------------------------------------------------------------
struct WtArgs {
  const float* W[6];
  bf16_t* Wt[6];
  int N[6];
  int e0[6];        // element offset of each matrix in the fused index space
};

__global__ __launch_bounds__(256) void wtrans6(WtArgs a) {
  int e = blockIdx.x * 256 + threadIdx.x;        // < 131072 by grid construction
  int c = 0;
#pragma unroll
  for (int i = 1; i < 6; i++) if (e >= a.e0[i]) c = i;
  int idx = e - a.e0[c];
  int N = a.N[c];
  int k = idx / N, n = idx - k * N;
  a.Wt[c][n * 128 + k] = (bf16_t)a.W[c][idx];
}

// ---------------------------------------------------------------------------
// Fused multi-config MFMA GEMM: Y[M,N] = bf16(X[M,128] @ W[128,N] + b).
// N = NT*16; per-block config selected by blockIdx range. Output bf16.
// A-frag: lane holds A[m=lane&15][k = kk*32 + quad*8 + j]
// C/D   : col = lane&15, row = quad*4 + reg   (verified gfx950 mapping)
// ---------------------------------------------------------------------------
template <int NT, int NCFG>
struct GemmArgs {
  const float* X[NCFG];
  const bf16_t* Wt[NCFG];
  const float* Bv[NCFG];
  bf16_t* Y[NCFG];
  int M[NCFG];
  int blk0[NCFG];
};

template <int NT, int NCFG>
__global__ __launch_bounds__(256) void mfma_gemm_multi(GemmArgs<NT, NCFG> a) {
  constexpr int N = NT * 16;
  int c = 0;
#pragma unroll
  for (int i = 1; i < NCFG; i++) if ((int)blockIdx.x >= a.blk0[i]) c = i;
  const float* X = a.X[c];
  const bf16_t* Wt = a.Wt[c];
  const float* B = a.Bv[c];
  bf16_t* Y = a.Y[c];
  int M = a.M[c];

  int wv = threadIdx.x >> 6, lane = threadIdx.x & 63;
  int m16 = lane & 15, quad = lane >> 4;
  int row0 = (blockIdx.x - a.blk0[c]) * 64 + wv * 16;
  int arow = row0 + m16;
  const float* xp = X + (size_t)arow * DIM + quad * 8;

  bf16x8 afrag[4];
#pragma unroll
  for (int kk = 0; kk < 4; kk++) {
    float4 lo = make_float4(0.f, 0.f, 0.f, 0.f), hi = lo;
    if (arow < M) {
      lo = *reinterpret_cast<const float4*>(xp + kk * 32);
      hi = *reinterpret_cast<const float4*>(xp + kk * 32 + 4);
    }
    bf16x8 av;
    av[0] = (bf16_t)lo.x; av[1] = (bf16_t)lo.y; av[2] = (bf16_t)lo.z; av[3] = (bf16_t)lo.w;
    av[4] = (bf16_t)hi.x; av[5] = (bf16_t)hi.y; av[6] = (bf16_t)hi.z; av[7] = (bf16_t)hi.w;
    afrag[kk] = av;
  }

#pragma unroll
  for (int nt = 0; nt < NT; nt++) {
    int col = nt * 16 + m16;
    const bf16_t* bptr = Wt + (size_t)col * DIM + quad * 8;
    floatx4 acc = {0.f, 0.f, 0.f, 0.f};
#pragma unroll
    for (int kk = 0; kk < 4; kk++) {
      bf16x8 b = *reinterpret_cast<const bf16x8*>(bptr + kk * 32);
      acc = __builtin_amdgcn_mfma_f32_16x16x32_bf16(afrag[kk], b, acc, 0, 0, 0);
    }
    float bias = B[col];
    int orow = row0 + quad * 4;
#pragma unroll
    for (int r = 0; r < 4; r++)
      if (orow + r < M) Y[(size_t)(orow + r) * N + col] = (bf16_t)(acc[r] + bias);
  }
}

// ---------------------------------------------------------------------------
// Small fp32 vector GEMM (self-loop linears, N in {32, 64}).
// ---------------------------------------------------------------------------
template <int N>
__global__ __launch_bounds__(256) void rowgemm(const float* __restrict__ X,
                                               const float* __restrict__ W,
                                               const float* __restrict__ B,
                                               float* __restrict__ Y, int M) {
  constexpr int TPR = N / 4;
  constexpr int R = 256 / TPR;
  __shared__ float xs[R * DIM];
  int row0 = blockIdx.x * R;
  for (int i = threadIdx.x * 4; i < R * DIM; i += 1024) {
    int gr = row0 + (i >> 7);
    float4 v = make_float4(0.f, 0.f, 0.f, 0.f);
    if (gr < M) v = *reinterpret_cast<const float4*>(X + (size_t)gr * DIM + (i & 127));
    *reinterpret_cast<float4*>(xs + i) = v;
  }
  __syncthreads();
  int r = threadIdx.x / TPR;
  int n0 = (threadIdx.x % TPR) * 4;
  int m = row0 + r;
  if (m >= M) return;
  const float* xrow = xs + r * DIM;
  float4 acc = make_float4(0.f, 0.f, 0.f, 0.f);
#pragma unroll 8
  for (int k = 0; k < DIM; k++) {
    float xk = xrow[k];
    float4 w = *reinterpret_cast<const float4*>(W + (size_t)k * N + n0);
    acc.x = fmaf(xk, w.x, acc.x);
    acc.y = fmaf(xk, w.y, acc.y);
    acc.z = fmaf(xk, w.z, acc.z);
    acc.w = fmaf(xk, w.w, acc.w);
  }
  float4 b = *reinterpret_cast<const float4*>(B + n0);
  acc.x += b.x; acc.y += b.y; acc.z += b.z; acc.w += b.w;
  *reinterpret_cast<float4*>(Y + (size_t)m * N + n0) = acc;
}

// ---------------------------------------------------------------------------
// Combined CSR build (sg rows [0,NG), gs rows [NG,NDST_TOT)).
// Scatter writes sorted (src, ea) payloads directly -> coalesced gather reads.
// ---------------------------------------------------------------------------
__global__ void hist2(const int* __restrict__ sgd, const int* __restrict__ gsd,
                      int* __restrict__ cnt) {
  int e = blockIdx.x * 256 + threadIdx.x;
  if (e >= NE) return;
  atomicAdd(cnt + sgd[e], 1);
  atomicAdd(cnt + NG + gsd[e], 1);
}

__global__ __launch_bounds__(1024) void scan1(const int* __restrict__ cnt,
                                              int* __restrict__ rp,
                                              int* __restrict__ csum, int n) {
  __shared__ int wsum[16];
  int i = blockIdx.x * 1024 + threadIdx.x;
  int lane = threadIdx.x & 63, w = threadIdx.x >> 6;
  int v = (i < n) ? cnt[i] : 0;
  int x = v;
#pragma unroll
  for (int off = 1; off < 64; off <<= 1) {
    int y = __shfl_up(x, off);
    if (lane >= off) x += y;
  }
  if (lane == 63) wsum[w] = x;
  __syncthreads();
  if (w == 0 && lane < 16) {
    int s = wsum[lane];
#pragma unroll
    for (int off = 1; off < 16; off <<= 1) {
      int y = __shfl_up(s, off);
      if (lane >= off) s += y;
    }
    wsum[lane] = s;
  }
  __syncthreads();
  int incl = x + (w ? wsum[w - 1] : 0);
  if (i < n) rp[i] = incl - v;
  if (threadIdx.x == 1023) csum[blockIdx.x] = incl;
}

__global__ void scan2(int* __restrict__ csum, int nb) {   // 1 wave, nb <= 64
  int lane = threadIdx.x;
  int v = (lane < nb) ? csum[lane] : 0;
  int x = v;
#pragma unroll
  for (int off = 1; off < 64; off <<= 1) {
    int y = __shfl_up(x, off);
    if (lane >= off) x += y;
  }
  if (lane < nb) csum[lane] = x - v;
}

__global__ __launch_bounds__(1024) void scan3(int* __restrict__ rp,
                                              const int* __restrict__ csum, int n) {
  int i = blockIdx.x * 1024 + threadIdx.x;
  if (i < n) rp[i] += csum[blockIdx.x];
  if (i == 0) rp[n] = 2 * NE;
}

__global__ void scatter2(const int* __restrict__ sgd, const int* __restrict__ gsd,
                         const int* __restrict__ sgs, const int* __restrict__ gss,
                         const float* __restrict__ easg, const float* __restrict__ eags,
                         const int* __restrict__ rp, int* __restrict__ cur,
                         int* __restrict__ srcS, float* __restrict__ eaS) {
  int t = blockIdx.x * 256 + threadIdx.x;
  if (t < NE) {
    int d = sgd[t];
    int pos = atomicAdd(cur + d, 1);
    int p = rp[d] + pos;
    srcS[p] = sgs[t];
    eaS[p] = easg[t];
  } else if (t < 2 * NE) {
    int e = t - NE;
    int d = gsd[e];
    int pos = atomicAdd(cur + NG + d, 1);
    int p = rp[NG + d] + pos;
    srcS[p] = gss[e];
    eaS[p] = eags[e];
  }
}

// ---------------------------------------------------------------------------
// GATv2 gather: SPLIT waves per destination node (LDS combine for SPLIT=2).
// xl, xr in bf16. Inner loop batches 8 edge-row gathers (MLP=8); tail edges
// repeat edge k0 with ex masked to 0. Metadata (src, ea) reads coalesced.
// MODE 0: out[d] = relu(acc/den + bo [+ sl tiled across heads])     (NC wide)
// MODE 1: out[d] = relu(mean_h(acc_h/den_h) + bo + sl)              (C wide)
// ---------------------------------------------------------------------------
template <int C, int MODE, int SPLIT>
__global__ __launch_bounds__(256) void gat_gather(
    const int* __restrict__ rp, const int* __restrict__ srcS,
    const float* __restrict__ eaS,
    const float* __restrict__ We, const float* __restrict__ att,
    const bf16_t* __restrict__ xl, const bf16_t* __restrict__ xr,
    const float* __restrict__ bo, const float* __restrict__ sl,
    float* __restrict__ out, int n_dst) {
  constexpr int NC = 4 * C;
  constexpr int VEC = NC / 64;
  constexpr int CH = 64 / SPLIT;     // edges staged per chunk per subwave
  typedef typename BV<VEC>::T bvec;
  int wv = threadIdx.x >> 6;
  int lane = threadIdx.x & 63;
  int gwave = blockIdx.x * 4 + wv;
  int d = (SPLIT == 2) ? (gwave >> 1) : gwave;
  int sub = (SPLIT == 2) ? (gwave & 1) : 0;
  bool active = d < n_dst;
  if (SPLIT == 1 && !active) return;

  float wev[VEC], atv[VEC], xrv[VEC], acc[VEC];
  if constexpr (VEC == 2) {
    *reinterpret_cast<float2*>(wev) = *reinterpret_cast<const float2*>(We + lane * VEC);
    *reinterpret_cast<float2*>(atv) = *reinterpret_cast<const float2*>(att + lane * VEC);
  } else {
    *reinterpret_cast<float4*>(wev) = *reinterpret_cast<const float4*>(We + lane * VEC);
    *reinterpret_cast<float4*>(atv) = *reinterpret_cast<const float4*>(att + lane * VEC);
  }
#pragma unroll
  for (int v = 0; v < VEC; v++) { xrv[v] = 0.f; acc[v] = 0.f; }
  if (active) {
    bvec xrb = *reinterpret_cast<const bvec*>(xr + (size_t)d * NC + lane * VEC);
#pragma unroll
    for (int v = 0; v < VEC; v++) xrv[v] = (float)xrb[v];
  }
  float den = 0.f;

  if (active) {
    int beg = rp[d], end = rp[d + 1];
    for (int i0 = beg + sub * CH; i0 < end; i0 += 64) {
      int cnt = min(CH, end - i0);
      int s_l = 0; float ea_l = 0.f;
      if (lane < cnt) {
        s_l = srcS[i0 + lane];
        ea_l = eaS[i0 + lane];
      }
      for (int k0 = 0; k0 < cnt; k0 += 8) {
        int s8[8]; float ea8[8];
        bvec raw[8];
#pragma unroll
        for (int g = 0; g < 8; g++) {
          int kk = (k0 + g < cnt) ? k0 + g : k0;
          s8[g] = __shfl(s_l, kk);
          ea8[g] = __shfl(ea_l, kk);
        }
#pragma unroll
        for (int g = 0; g < 8; g++)
          raw[g] = *reinterpret_cast<const bvec*>(xl + (size_t)s8[g] * NC + lane * VEC);
#pragma unroll
        for (int g = 0; g < 8; g++) {
          float xf[VEC];
          float p = 0.f;
#pragma unroll
          for (int v = 0; v < VEC; v++) {
            xf[v] = (float)raw[g][v];
            float mm = xf[v] + xrv[v] + ea8[g] * wev[v];
            mm = mm > 0.f ? mm : 0.2f * mm;      // leaky_relu(., 0.2)
            p = fmaf(mm, atv[v], p);
          }
          p += __shfl_xor(p, 1);
          p += __shfl_xor(p, 2);
          p += __shfl_xor(p, 4);
          p += __shfl_xor(p, 8);                 // head-wide logit
          float ex = __expf(p);
          if (k0 + g >= cnt) ex = 0.f;           // mask tail repeats
          den += ex;
#pragma unroll
          for (int v = 0; v < VEC; v++) acc[v] = fmaf(ex, xf[v], acc[v]);
        }
      }
    }
  }

  if constexpr (SPLIT == 2) {
    __shared__ float lacc[2][64 * VEC];
    __shared__ float lden[2][64];
    int pair = wv >> 1;
    if (sub == 1) {
#pragma unroll
      for (int v = 0; v < VEC; v++) lacc[pair][lane * VEC + v] = acc[v];
      lden[pair][lane] = den;
    }
    __syncthreads();
    if (sub == 1 || !active) return;
#pragma unroll
    for (int v = 0; v < VEC; v++) acc[v] += lacc[pair][lane * VEC + v];
    den += lden[pair][lane];
  }

  float inv = den > 0.f ? 1.f / den : 0.f;
  if constexpr (MODE == 0) {
#pragma unroll
    for (int v = 0; v < VEC; v++) {
      int j = lane * VEC + v;
      float val = acc[v] * inv + bo[j];
      if (sl) val += sl[(size_t)d * C + (j & (C - 1))];
      out[(size_t)d * NC + j] = val > 0.f ? val : 0.f;
    }
  } else {
#pragma unroll
    for (int v = 0; v < VEC; v++) {
      float s_ = acc[v] * inv;
      s_ += __shfl_xor(s_, 16);
      s_ += __shfl_xor(s_, 32);                  // sum over the 4 heads
      if (lane < 16) {
        int c = (lane & 15) * VEC + v;
        float val = 0.25f * s_ + bo[c] + sl[(size_t)d * C + c];
        out[(size_t)d * C + c] = val > 0.f ? val : 0.f;
      }
    }
  }
}

// ---------------------------------------------------------------------------

static inline int nblk(long long threads) { return (int)((threads + 255) / 256); }
static inline int nrow(int M, int R) { return (M + R - 1) / R; }

extern "C" void kernel_launch(void* const* d_in, const int* in_sizes, int n_in,
                              void* d_out, int out_size, void* d_ws, size_t ws_size,
                              hipStream_t stream) {
  const float* x_mrna = (const float*)d_in[0];
  const float* x_gene = (const float*)d_in[1];
  const int* sg_src = (const int*)d_in[2];
  const int* sg_dst = (const int*)d_in[3];
  const int* gs_src = (const int*)d_in[4];
  const int* gs_dst = (const int*)d_in[5];
  const float* ea_sg = (const float*)d_in[6];
  const float* ea_gs = (const float*)d_in[7];
  const float* Wl1_sg = (const float*)d_in[8];
  const float* bl1_sg = (const float*)d_in[9];
  const float* Wr1_sg = (const float*)d_in[10];
  const float* br1_sg = (const float*)d_in[11];
  const float* We1_sg = (const float*)d_in[12];
  const float* att1_sg = (const float*)d_in[13];
  const float* bo1_sg = (const float*)d_in[14];
  const float* Wl1_gs = (const float*)d_in[15];
  const float* bl1_gs = (const float*)d_in[16];
  const float* Wr1_gs = (const float*)d_in[17];
  const float* br1_gs = (const float*)d_in[18];
  const float* We1_gs = (const float*)d_in[19];
  const float* att1_gs = (const float*)d_in[20];
  const float* bo1_gs = (const float*)d_in[21];
  const float* Wl3_gs = (const float*)d_in[22];
  const float* bl3_gs = (const float*)d_in[23];
  const float* Wr3_gs = (const float*)d_in[24];
  const float* br3_gs = (const float*)d_in[25];
  const float* We3_gs = (const float*)d_in[26];
  const float* att3_gs = (const float*)d_in[27];
  const float* bo3_gs = (const float*)d_in[28];
  const float* Wsl1 = (const float*)d_in[29];
  const float* bsl1 = (const float*)d_in[30];
  const float* Wsl3 = (const float*)d_in[31];
  const float* bsl3 = (const float*)d_in[32];

  // ---- workspace arena (fp32 element offsets) ----
  // All GEMM outputs bf16. Phase-D outputs alias the dead phase-B region.
  float* ws = (float*)d_ws;
  bf16_t* xl1_gs = (bf16_t*)(ws + 0);        // bf16[50000*128] (3.2M fl)
  bf16_t* xl1_sg = (bf16_t*)(ws + 3200000);  // bf16[4000*128]  (0.256M fl)
  bf16_t* xr1_sg = (bf16_t*)(ws + 3456000);  // bf16[50000*128] (3.2M fl)
  bf16_t* xr1_gs = (bf16_t*)(ws + 6656000);  // bf16[4000*128]  (0.256M fl) -> 6.912M
  bf16_t* xl3    = (bf16_t*)(ws + 0);        // bf16[50000*256] (6.4M fl) aliases dead B
  bf16_t* xr3    = (bf16_t*)(ws + 6400000);  // bf16[4000*256]  (0.512M fl) aliases dead B
  float* x1_gene = ws + 6912000;   // [50000*128] -> 13.312M
  float* x1_mrna = ws + 13312000;  // [4000*128]  -> 13.824M
  float* sl1     = ws + 13824000;  // [4000*32]   -> 13.952M
  float* sl3     = ws + 13952000;  // [4000*64]   -> 14.208M
  int*   ib      = (int*)(ws + 14208000);
  int* cnt  = ib + 0;              // [54000] } zeroed by one memset; dead after
  int* cur  = ib + 54000;          // [54000] } phase A -> overlaid by bf16 Wt
  int* rpc  = ib + 108000;         // [54001] combined row pointers
  int* csum = ib + 162016;         // [64]
  int* srcS = ib + 162080;         // [500000] CSR-sorted src ids
  float* eaS = (float*)(ib + 662080);  // [500000] CSR-sorted edge attrs
  // end: ib + 1162080 -> total ~61.5 MB

  // bf16 transposed weights overlay dead cnt/cur (432 KB avail, need 256 KB)
  bf16_t* wtb = (bf16_t*)cnt;
  bf16_t* wt_l1sg = wtb + 0;
  bf16_t* wt_r1sg = wtb + 16384;
  bf16_t* wt_l1gs = wtb + 32768;
  bf16_t* wt_r1gs = wtb + 49152;
  bf16_t* wt_l3   = wtb + 65536;   // [256*128]
  bf16_t* wt_r3   = wtb + 98304;   // [256*128]

  // zero CSR counters (ws is poisoned 0xAA before every timed call)
  hipMemsetAsync(cnt, 0, 108000 * sizeof(int), stream);

  // ---- phase A: combined CSR build with sorted edge payloads ----
  hist2<<<nblk(NE), 256, 0, stream>>>(sg_dst, gs_dst, cnt);
  int nchunks = (NDST_TOT + 1023) / 1024;            // 53
  scan1<<<nchunks, 1024, 0, stream>>>(cnt, rpc, csum, NDST_TOT);
  scan2<<<1, 64, 0, stream>>>(csum, nchunks);
  scan3<<<nchunks, 1024, 0, stream>>>(rpc, csum, NDST_TOT);
  scatter2<<<nblk(2LL * NE), 256, 0, stream>>>(sg_dst, gs_dst, sg_src, gs_src,
                                               ea_sg, ea_gs, rpc, cur, srcS, eaS);

  // ---- phase A2: fused weight transpose + bf16 cast (cnt/cur now dead) ----
  {
    WtArgs wa;
    const float* Wsrc[6] = {Wl1_sg, Wr1_sg, Wl1_gs, Wr1_gs, Wl3_gs, Wr3_gs};
    bf16_t* Wdst[6] = {wt_l1sg, wt_r1sg, wt_l1gs, wt_r1gs, wt_l3, wt_r3};
    int Nn[6] = {128, 128, 128, 128, 256, 256};
    int e0[6] = {0, 16384, 32768, 49152, 65536, 98304};
    for (int i = 0; i < 6; i++) { wa.W[i] = Wsrc[i]; wa.Wt[i] = Wdst[i]; wa.N[i] = Nn[i]; wa.e0[i] = e0[i]; }
    wtrans6<<<512, 256, 0, stream>>>(wa);
  }

  // ---- phase B: fused layer-1 node GEMMs (bf16 MFMA, bf16 out) ----
  {
    GemmArgs<8, 4> ga;
    const float* Xs[4] = {x_mrna, x_gene, x_gene, x_mrna};
    const bf16_t* Ws[4] = {wt_l1sg, wt_r1sg, wt_l1gs, wt_r1gs};
    const float* Bs[4] = {bl1_sg, br1_sg, bl1_gs, br1_gs};
    bf16_t* Ys[4] = {xl1_sg, xr1_sg, xl1_gs, xr1_gs};
    int Ms[4] = {NS, NG, NG, NS};
    int b0 = 0;
    for (int i = 0; i < 4; i++) {
      ga.X[i] = Xs[i]; ga.Wt[i] = Ws[i]; ga.Bv[i] = Bs[i]; ga.Y[i] = Ys[i];
      ga.M[i] = Ms[i]; ga.blk0[i] = b0;
      b0 += nrow(Ms[i], 64);
    }
    mfma_gemm_multi<8, 4><<<b0, 256, 0, stream>>>(ga);   // 1690 blocks
  }
  rowgemm<32><<<nrow(NS, 32), 256, 0, stream>>>(x_mrna, Wsl1, bsl1, sl1, NS);

  // ---- phase C: layer-1 gathers (fused bias/self-loop/relu epilogue) ----
  gat_gather<32, 0, 1><<<nblk((long long)NG * 64), 256, 0, stream>>>(
      rpc, srcS, eaS, We1_sg, att1_sg, xl1_sg, xr1_sg,
      bo1_sg, (const float*)nullptr, x1_gene, NG);
  gat_gather<32, 0, 2><<<nblk((long long)NS * 2 * 64), 256, 0, stream>>>(
      rpc + NG, srcS, eaS, We1_gs, att1_gs, xl1_gs, xr1_gs,
      bo1_gs, sl1, x1_mrna, NS);

  // ---- phase D: fused layer-3 node GEMMs ----
  {
    GemmArgs<16, 2> ga;
    const float* Xs[2] = {x1_gene, x1_mrna};
    const bf16_t* Ws[2] = {wt_l3, wt_r3};
    const float* Bs[2] = {bl3_gs, br3_gs};
    bf16_t* Ys[2] = {xl3, xr3};
    int Ms[2] = {NG, NS};
    int b0 = 0;
    for (int i = 0; i < 2; i++) {
      ga.X[i] = Xs[i]; ga.Wt[i] = Ws[i]; ga.Bv[i] = Bs[i]; ga.Y[i] = Ys[i];
      ga.M[i] = Ms[i]; ga.blk0[i] = b0;
      b0 += nrow(Ms[i], 64);
    }
    mfma_gemm_multi<16, 2><<<b0, 256, 0, stream>>>(ga);  // 845 blocks
  }
  rowgemm<64><<<nrow(NS, 16), 256, 0, stream>>>(x1_mrna, Wsl3, bsl3, sl3, NS);

  // ---- phase E: layer-3 gather (fused head-mean/self-loop/relu) -> d_out ----
  gat_gather<64, 1, 2><<<nblk((long long)NS * 2 * 64), 256, 0, stream>>>(
      rpc + NG, srcS, eaS, We3_gs, att3_gs, xl3, xr3,
      bo3_gs, sl3, (float*)d_out, NS);
}

// Round 7
// 392.946 us; speedup vs baseline: 4.7965x; 1.0425x over previous
//
#include <hip/hip_runtime.h>
#include <cstdint>
#include <cstddef>

// Problem constants (match reference)
#define NS 4000
#define NG 50000
#define NE 250000
#define DIM 128
#define NDST_TOT (NG + NS)          // 54000 combined CSR rows (sg then gs)

typedef __bf16 bf16_t;
typedef bf16_t bf16x8 __attribute__((ext_vector_type(8)));
typedef bf16_t bf16x4 __attribute__((ext_vector_type(4)));
typedef float floatx4 __attribute__((ext_vector_type(4)));

template <int V> struct BV {};
template <> struct BV<2> { typedef bf16_t T __attribute__((ext_vector_type(2))); };
template <> struct BV<4> { typedef bf16_t T __attribute__((ext_vector_type(4))); };

// ---------------------------------------------------------------------------
// Fused prep: 6 weight transposes (Wt[n][k] = bf16(W[k][n])) + bf16 casts of
// x_mrna and x_gene. Segments: [0,131072) wt, then 128000 x4-casts (x_mrna),
// then 1600000 x4-casts (x_gene). Total threads = 1859072 = 7262 * 256.
// ---------------------------------------------------------------------------
struct PrepArgs {
  const float* W[6];
  bf16_t* Wt[6];
  int N[6];
  int e0[6];
  const float* xm; bf16_t* xbm;
  const float* xg; bf16_t* xbg;
};

__global__ __launch_bounds__(256) void prep(PrepArgs a) {
  int t = blockIdx.x * 256 + threadIdx.x;
  if (t < 131072) {
    int c = 0;
#pragma unroll
    for (int i = 1; i < 6; i++) if (t >= a.e0[i]) c = i;
    int idx = t - a.e0[c];
    int N = a.N[c];
    int k = idx / N, n = idx - k * N;
    a.Wt[c][n * 128 + k] = (bf16_t)a.W[c][idx];
  } else if (t < 131072 + 128000) {
    int j = (t - 131072) * 4;
    float4 v = *reinterpret_cast<const float4*>(a.xm + j);
    bf16x4 b;
    b[0] = (bf16_t)v.x; b[1] = (bf16_t)v.y; b[2] = (bf16_t)v.z; b[3] = (bf16_t)v.w;
    *reinterpret_cast<bf16x4*>(a.xbm + j) = b;
  } else {
    int j = (t - 131072 - 128000) * 4;
    float4 v = *reinterpret_cast<const float4*>(a.xg + j);
    bf16x4 b;
    b[0] = (bf16_t)v.x; b[1] = (bf16_t)v.y; b[2] = (bf16_t)v.z; b[3] = (bf16_t)v.w;
    *reinterpret_cast<bf16x4*>(a.xbg + j) = b;
  }
}

// ---------------------------------------------------------------------------
// Fused multi-config MFMA GEMM: Y[M,N] = bf16(X[M,128] @ W[128,N] + b).
// X now bf16 (16B A-frag loads). N = NT*16; config by blockIdx range.
// C/D: col = lane&15, row = quad*4 + reg   (verified gfx950 mapping)
// ---------------------------------------------------------------------------
template <int NT, int NCFG>
struct GemmArgs {
  const bf16_t* X[NCFG];
  const bf16_t* Wt[NCFG];
  const float* Bv[NCFG];
  bf16_t* Y[NCFG];
  int M[NCFG];
  int blk0[NCFG];
};

template <int NT, int NCFG>
__global__ __launch_bounds__(256) void mfma_gemm_multi(GemmArgs<NT, NCFG> a) {
  constexpr int N = NT * 16;
  int c = 0;
#pragma unroll
  for (int i = 1; i < NCFG; i++) if ((int)blockIdx.x >= a.blk0[i]) c = i;
  const bf16_t* X = a.X[c];
  const bf16_t* Wt = a.Wt[c];
  const float* B = a.Bv[c];
  bf16_t* Y = a.Y[c];
  int M = a.M[c];

  int wv = threadIdx.x >> 6, lane = threadIdx.x & 63;
  int m16 = lane & 15, quad = lane >> 4;
  int row0 = (blockIdx.x - a.blk0[c]) * 64 + wv * 16;
  int arow = row0 + m16;
  const bf16_t* xp = X + (size_t)arow * DIM + quad * 8;

  bf16x8 afrag[4];
#pragma unroll
  for (int kk = 0; kk < 4; kk++) {
    bf16x8 av = {};
    if (arow < M) av = *reinterpret_cast<const bf16x8*>(xp + kk * 32);
    afrag[kk] = av;
  }

#pragma unroll
  for (int nt = 0; nt < NT; nt++) {
    int col = nt * 16 + m16;
    const bf16_t* bptr = Wt + (size_t)col * DIM + quad * 8;
    floatx4 acc = {0.f, 0.f, 0.f, 0.f};
#pragma unroll
    for (int kk = 0; kk < 4; kk++) {
      bf16x8 b = *reinterpret_cast<const bf16x8*>(bptr + kk * 32);
      acc = __builtin_amdgcn_mfma_f32_16x16x32_bf16(afrag[kk], b, acc, 0, 0, 0);
    }
    float bias = B[col];
    int orow = row0 + quad * 4;
#pragma unroll
    for (int r = 0; r < 4; r++)
      if (orow + r < M) Y[(size_t)(orow + r) * N + col] = (bf16_t)(acc[r] + bias);
  }
}

// ---------------------------------------------------------------------------
// Small fp32 vector GEMM (self-loop linears); TIN = bf16 input.
// ---------------------------------------------------------------------------
template <int N, typename TIN>
__global__ __launch_bounds__(256) void rowgemm(const TIN* __restrict__ X,
                                               const float* __restrict__ W,
                                               const float* __restrict__ B,
                                               float* __restrict__ Y, int M) {
  constexpr int TPR = N / 4;
  constexpr int R = 256 / TPR;
  __shared__ float xs[R * DIM];
  int row0 = blockIdx.x * R;
  for (int i = threadIdx.x * 4; i < R * DIM; i += 1024) {
    int gr = row0 + (i >> 7);
    float4 v = make_float4(0.f, 0.f, 0.f, 0.f);
    if (gr < M) {
      if constexpr (sizeof(TIN) == 2) {
        bf16x4 b = *reinterpret_cast<const bf16x4*>((const bf16_t*)X + (size_t)gr * DIM + (i & 127));
        v = make_float4((float)b[0], (float)b[1], (float)b[2], (float)b[3]);
      } else {
        v = *reinterpret_cast<const float4*>((const float*)X + (size_t)gr * DIM + (i & 127));
      }
    }
    *reinterpret_cast<float4*>(xs + i) = v;
  }
  __syncthreads();
  int r = threadIdx.x / TPR;
  int n0 = (threadIdx.x % TPR) * 4;
  int m = row0 + r;
  if (m >= M) return;
  const float* xrow = xs + r * DIM;
  float4 acc = make_float4(0.f, 0.f, 0.f, 0.f);
#pragma unroll 8
  for (int k = 0; k < DIM; k++) {
    float xk = xrow[k];
    float4 w = *reinterpret_cast<const float4*>(W + (size_t)k * N + n0);
    acc.x = fmaf(xk, w.x, acc.x);
    acc.y = fmaf(xk, w.y, acc.y);
    acc.z = fmaf(xk, w.z, acc.z);
    acc.w = fmaf(xk, w.w, acc.w);
  }
  float4 b = *reinterpret_cast<const float4*>(B + n0);
  acc.x += b.x; acc.y += b.y; acc.z += b.z; acc.w += b.w;
  *reinterpret_cast<float4*>(Y + (size_t)m * N + n0) = acc;
}

// ---------------------------------------------------------------------------
// Combined CSR build; scatter writes packed (src, ea) uint2 payloads sorted.
// ---------------------------------------------------------------------------
__global__ void hist2(const int* __restrict__ sgd, const int* __restrict__ gsd,
                      int* __restrict__ cnt) {
  int e = blockIdx.x * 256 + threadIdx.x;
  if (e >= NE) return;
  atomicAdd(cnt + sgd[e], 1);
  atomicAdd(cnt + NG + gsd[e], 1);
}

__global__ __launch_bounds__(1024) void scan1(const int* __restrict__ cnt,
                                              int* __restrict__ rp,
                                              int* __restrict__ csum, int n) {
  __shared__ int wsum[16];
  int i = blockIdx.x * 1024 + threadIdx.x;
  int lane = threadIdx.x & 63, w = threadIdx.x >> 6;
  int v = (i < n) ? cnt[i] : 0;
  int x = v;
#pragma unroll
  for (int off = 1; off < 64; off <<= 1) {
    int y = __shfl_up(x, off);
    if (lane >= off) x += y;
  }
  if (lane == 63) wsum[w] = x;
  __syncthreads();
  if (w == 0 && lane < 16) {
    int s = wsum[lane];
#pragma unroll
    for (int off = 1; off < 16; off <<= 1) {
      int y = __shfl_up(s, off);
      if (lane >= off) s += y;
    }
    wsum[lane] = s;
  }
  __syncthreads();
  int incl = x + (w ? wsum[w - 1] : 0);
  if (i < n) rp[i] = incl - v;
  if (threadIdx.x == 1023) csum[blockIdx.x] = incl;
}

__global__ void scan2(int* __restrict__ csum, int nb) {   // 1 wave, nb <= 64
  int lane = threadIdx.x;
  int v = (lane < nb) ? csum[lane] : 0;
  int x = v;
#pragma unroll
  for (int off = 1; off < 64; off <<= 1) {
    int y = __shfl_up(x, off);
    if (lane >= off) x += y;
  }
  if (lane < nb) csum[lane] = x - v;
}

__global__ __launch_bounds__(1024) void scan3(int* __restrict__ rp,
                                              const int* __restrict__ csum, int n) {
  int i = blockIdx.x * 1024 + threadIdx.x;
  if (i < n) rp[i] += csum[blockIdx.x];
  if (i == 0) rp[n] = 2 * NE;
}

__global__ void scatter2(const int* __restrict__ sgd, const int* __restrict__ gsd,
                         const int* __restrict__ sgs, const int* __restrict__ gss,
                         const float* __restrict__ easg, const float* __restrict__ eags,
                         const int* __restrict__ rp, int* __restrict__ cur,
                         uint2* __restrict__ meta) {
  int t = blockIdx.x * 256 + threadIdx.x;
  if (t < NE) {
    int d = sgd[t];
    int pos = atomicAdd(cur + d, 1);
    uint2 pv; pv.x = (unsigned)sgs[t]; pv.y = __float_as_uint(easg[t]);
    meta[rp[d] + pos] = pv;
  } else if (t < 2 * NE) {
    int e = t - NE;
    int d = gsd[e];
    int pos = atomicAdd(cur + NG + d, 1);
    uint2 pv; pv.x = (unsigned)gss[e]; pv.y = __float_as_uint(eags[e]);
    meta[rp[NG + d] + pos] = pv;
  }
}

// ---------------------------------------------------------------------------
// sg layer-1 gather: one wave per TWO destinations (CSR rows contiguous ->
// one rp triple + one metadata stage covers both). Flag-weighted dual acc.
// C=32, VEC=2. Output bf16, fused bias+relu.
// ---------------------------------------------------------------------------
__global__ __launch_bounds__(256) void gat_sg(
    const int* __restrict__ rp, const uint2* __restrict__ meta,
    const float* __restrict__ We, const float* __restrict__ att,
    const bf16_t* __restrict__ xl, const bf16_t* __restrict__ xr,
    const float* __restrict__ bo, bf16_t* __restrict__ out, int n_dst) {
  typedef BV<2>::T bvec;
  int wid = (blockIdx.x * 256 + threadIdx.x) >> 6;
  int lane = threadIdx.x & 63;
  int d0 = wid * 2;
  if (d0 >= n_dst) return;                    // n_dst even -> d0+1 valid
  int q = lane < 3 ? lane : 0;
  int rv = rp[d0 + q];                        // rp[d0], rp[d0+1], rp[d0+2]
  int b0 = __shfl(rv, 0), m = __shfl(rv, 1), e1 = __shfl(rv, 2);

  float2 wev = *reinterpret_cast<const float2*>(We + lane * 2);
  float2 atv = *reinterpret_cast<const float2*>(att + lane * 2);
  bvec x0b = *reinterpret_cast<const bvec*>(xr + (size_t)d0 * 128 + lane * 2);
  bvec x1b = *reinterpret_cast<const bvec*>(xr + (size_t)(d0 + 1) * 128 + lane * 2);
  float xr0[2] = {(float)x0b[0], (float)x0b[1]};
  float xr1[2] = {(float)x1b[0], (float)x1b[1]};
  float acc0[2] = {0.f, 0.f}, acc1[2] = {0.f, 0.f};
  float den0 = 0.f, den1 = 0.f;

  for (int i0 = b0; i0 < e1; i0 += 64) {
    int cnt = min(64, e1 - i0);
    int s_l = 0; float ea_l = 0.f;
    if (lane < cnt) {
      uint2 mv = meta[i0 + lane];
      s_l = (int)mv.x; ea_l = __uint_as_float(mv.y);
    }
    for (int k0 = 0; k0 < cnt; k0 += 8) {
      int s8[8], gi[8]; float ea8[8];
      bvec raw[8];
#pragma unroll
      for (int g = 0; g < 8; g++) {
        int kk = (k0 + g < cnt) ? k0 + g : k0;
        s8[g] = __shfl(s_l, kk);
        ea8[g] = __shfl(ea_l, kk);
        gi[g] = i0 + kk;
      }
#pragma unroll
      for (int g = 0; g < 8; g++)
        raw[g] = *reinterpret_cast<const bvec*>(xl + (size_t)s8[g] * 128 + lane * 2);
#pragma unroll
      for (int g = 0; g < 8; g++) {
        bool f0 = gi[g] < m;
        float xs0 = f0 ? xr0[0] : xr1[0];
        float xs1 = f0 ? xr0[1] : xr1[1];
        float xf0 = (float)raw[g][0], xf1 = (float)raw[g][1];
        float m0 = xf0 + xs0 + ea8[g] * wev.x;
        float m1 = xf1 + xs1 + ea8[g] * wev.y;
        m0 = m0 > 0.f ? m0 : 0.2f * m0;        // leaky_relu(., 0.2)
        m1 = m1 > 0.f ? m1 : 0.2f * m1;
        float p = fmaf(m0, atv.x, m1 * atv.y);
        p += __shfl_xor(p, 1);
        p += __shfl_xor(p, 2);
        p += __shfl_xor(p, 4);
        p += __shfl_xor(p, 8);                 // head-wide logit
        float ex = __expf(p);
        if (k0 + g >= cnt) ex = 0.f;           // mask tail repeats
        float w0 = f0 ? ex : 0.f;
        float w1 = ex - w0;
        den0 += w0; den1 += w1;
        acc0[0] = fmaf(w0, xf0, acc0[0]); acc0[1] = fmaf(w0, xf1, acc0[1]);
        acc1[0] = fmaf(w1, xf0, acc1[0]); acc1[1] = fmaf(w1, xf1, acc1[1]);
      }
    }
  }
  int j = lane * 2;
  float i0v = den0 > 0.f ? 1.f / den0 : 0.f;
  float i1v = den1 > 0.f ? 1.f / den1 : 0.f;
  float bo0 = bo[j], bo1 = bo[j + 1];
  bvec o0, o1;
  o0[0] = (bf16_t)fmaxf(acc0[0] * i0v + bo0, 0.f);
  o0[1] = (bf16_t)fmaxf(acc0[1] * i0v + bo1, 0.f);
  o1[0] = (bf16_t)fmaxf(acc1[0] * i1v + bo0, 0.f);
  o1[1] = (bf16_t)fmaxf(acc1[1] * i1v + bo1, 0.f);
  *reinterpret_cast<bvec*>(out + (size_t)d0 * 128 + j) = o0;
  *reinterpret_cast<bvec*>(out + (size_t)(d0 + 1) * 128 + j) = o1;
}

// ---------------------------------------------------------------------------
// gs gathers: one BLOCK (4 subwaves) per destination, LDS combine.
// MODE 0: out bf16 = relu(acc/den + bo + sl tiled)       (NC wide)
// MODE 1: out fp32 = relu(mean_h(acc_h/den_h) + bo + sl) (C wide)
// ---------------------------------------------------------------------------
template <int C, int MODE, typename TOUT>
__global__ __launch_bounds__(256) void gat_gather4(
    const int* __restrict__ rp, const uint2* __restrict__ meta,
    const float* __restrict__ We, const float* __restrict__ att,
    const bf16_t* __restrict__ xl, const bf16_t* __restrict__ xr,
    const float* __restrict__ bo, const float* __restrict__ sl,
    TOUT* __restrict__ out, int n_dst) {
  constexpr int NC = 4 * C;
  constexpr int VEC = NC / 64;
  constexpr int CH = 16;
  typedef typename BV<VEC>::T bvec;
  __shared__ float lacc[4][64 * VEC];
  __shared__ float lden[4][64];
  int wv = threadIdx.x >> 6, lane = threadIdx.x & 63;
  int d = blockIdx.x;

  float wev[VEC], atv[VEC], xrv[VEC], acc[VEC];
  if constexpr (VEC == 2) {
    *reinterpret_cast<float2*>(wev) = *reinterpret_cast<const float2*>(We + lane * VEC);
    *reinterpret_cast<float2*>(atv) = *reinterpret_cast<const float2*>(att + lane * VEC);
  } else {
    *reinterpret_cast<float4*>(wev) = *reinterpret_cast<const float4*>(We + lane * VEC);
    *reinterpret_cast<float4*>(atv) = *reinterpret_cast<const float4*>(att + lane * VEC);
  }
  bvec xrb = *reinterpret_cast<const bvec*>(xr + (size_t)d * NC + lane * VEC);
#pragma unroll
  for (int v = 0; v < VEC; v++) { xrv[v] = (float)xrb[v]; acc[v] = 0.f; }
  float den = 0.f;

  int beg = rp[d], end = rp[d + 1];
  for (int i0 = beg + wv * CH; i0 < end; i0 += 64) {
    int cnt = min(CH, end - i0);
    int s_l = 0; float ea_l = 0.f;
    if (lane < cnt) {
      uint2 mv = meta[i0 + lane];
      s_l = (int)mv.x; ea_l = __uint_as_float(mv.y);
    }
    for (int k0 = 0; k0 < cnt; k0 += 8) {
      int s8[8]; float ea8[8];
      bvec raw[8];
#pragma unroll
      for (int g = 0; g < 8; g++) {
        int kk = (k0 + g < cnt) ? k0 + g : k0;
        s8[g] = __shfl(s_l, kk);
        ea8[g] = __shfl(ea_l, kk);
      }
#pragma unroll
      for (int g = 0; g < 8; g++)
        raw[g] = *reinterpret_cast<const bvec*>(xl + (size_t)s8[g] * NC + lane * VEC);
#pragma unroll
      for (int g = 0; g < 8; g++) {
        float xf[VEC];
        float p = 0.f;
#pragma unroll
        for (int v = 0; v < VEC; v++) {
          xf[v] = (float)raw[g][v];
          float mm = xf[v] + xrv[v] + ea8[g] * wev[v];
          mm = mm > 0.f ? mm : 0.2f * mm;        // leaky_relu(., 0.2)
          p = fmaf(mm, atv[v], p);
        }
        p += __shfl_xor(p, 1);
        p += __shfl_xor(p, 2);
        p += __shfl_xor(p, 4);
        p += __shfl_xor(p, 8);
        float ex = __expf(p);
        if (k0 + g >= cnt) ex = 0.f;
        den += ex;
#pragma unroll
        for (int v = 0; v < VEC; v++) acc[v] = fmaf(ex, xf[v], acc[v]);
      }
    }
  }

#pragma unroll
  for (int v = 0; v < VEC; v++) lacc[wv][lane * VEC + v] = acc[v];
  lden[wv][lane] = den;
  __syncthreads();
  if (wv != 0) return;
#pragma unroll
  for (int s = 1; s < 4; s++) {
#pragma unroll
    for (int v = 0; v < VEC; v++) acc[v] += lacc[s][lane * VEC + v];
    den += lden[s][lane];
  }

  float inv = den > 0.f ? 1.f / den : 0.f;
  if constexpr (MODE == 0) {
    bvec o;
#pragma unroll
    for (int v = 0; v < VEC; v++) {
      int j = lane * VEC + v;
      float val = acc[v] * inv + bo[j] + sl[(size_t)d * C + (j & (C - 1))];
      o[v] = (bf16_t)(val > 0.f ? val : 0.f);
    }
    *reinterpret_cast<bvec*>((bf16_t*)out + (size_t)d * NC + lane * VEC) = o;
  } else {
#pragma unroll
    for (int v = 0; v < VEC; v++) {
      float s_ = acc[v] * inv;
      s_ += __shfl_xor(s_, 16);
      s_ += __shfl_xor(s_, 32);                  // sum over the 4 heads
      if (lane < 16) {
        int c = (lane & 15) * VEC + v;
        float val = 0.25f * s_ + bo[c] + sl[(size_t)d * C + c];
        ((float*)out)[(size_t)d * C + c] = val > 0.f ? val : 0.f;
      }
    }
  }
}

// ---------------------------------------------------------------------------

static inline int nblk(long long threads) { return (int)((threads + 255) / 256); }
static inline int nrow(int M, int R) { return (M + R - 1) / R; }

extern "C" void kernel_launch(void* const* d_in, const int* in_sizes, int n_in,
                              void* d_out, int out_size, void* d_ws, size_t ws_size,
                              hipStream_t stream) {
  const float* x_mrna = (const float*)d_in[0];
  const float* x_gene = (const float*)d_in[1];
  const int* sg_src = (const int*)d_in[2];
  const int* sg_dst = (const int*)d_in[3];
  const int* gs_src = (const int*)d_in[4];
  const int* gs_dst = (const int*)d_in[5];
  const float* ea_sg = (const float*)d_in[6];
  const float* ea_gs = (const float*)d_in[7];
  const float* Wl1_sg = (const float*)d_in[8];
  const float* bl1_sg = (const float*)d_in[9];
  const float* Wr1_sg = (const float*)d_in[10];
  const float* br1_sg = (const float*)d_in[11];
  const float* We1_sg = (const float*)d_in[12];
  const float* att1_sg = (const float*)d_in[13];
  const float* bo1_sg = (const float*)d_in[14];
  const float* Wl1_gs = (const float*)d_in[15];
  const float* bl1_gs = (const float*)d_in[16];
  const float* Wr1_gs = (const float*)d_in[17];
  const float* br1_gs = (const float*)d_in[18];
  const float* We1_gs = (const float*)d_in[19];
  const float* att1_gs = (const float*)d_in[20];
  const float* bo1_gs = (const float*)d_in[21];
  const float* Wl3_gs = (const float*)d_in[22];
  const float* bl3_gs = (const float*)d_in[23];
  const float* Wr3_gs = (const float*)d_in[24];
  const float* br3_gs = (const float*)d_in[25];
  const float* We3_gs = (const float*)d_in[26];
  const float* att3_gs = (const float*)d_in[27];
  const float* bo3_gs = (const float*)d_in[28];
  const float* Wsl1 = (const float*)d_in[29];
  const float* bsl1 = (const float*)d_in[30];
  const float* Wsl3 = (const float*)d_in[31];
  const float* bsl3 = (const float*)d_in[32];

  // ---- workspace arena (fp32 element offsets), bf16 throughout ----
  float* ws = (float*)d_ws;
  bf16_t* xl1_gs = (bf16_t*)(ws + 0);        // bf16[50000*128] dead after C
  bf16_t* xl1_sg = (bf16_t*)(ws + 3200000);  // bf16[4000*128]  dead after C
  bf16_t* xr1_sg = (bf16_t*)(ws + 3456000);  // bf16[50000*128] dead after C
  bf16_t* xr1_gs = (bf16_t*)(ws + 6656000);  // bf16[4000*128]  dead after C
  bf16_t* xl3    = (bf16_t*)(ws + 0);        // bf16[50000*256] aliases [0,6.4M)
  bf16_t* xr3    = (bf16_t*)(ws + 6400000);  // bf16[4000*256]  aliases [6.4M,6.656M)
  bf16_t* xb_mrna = (bf16_t*)(ws + 6912000); // bf16[4000*128]
  bf16_t* xb_gene = (bf16_t*)(ws + 7168000); // bf16[50000*128]
  bf16_t* x1_gene = (bf16_t*)(ws + 10368000);// bf16[50000*128]
  bf16_t* x1_mrna = (bf16_t*)(ws + 13568000);// bf16[4000*128]
  float* sl1     = ws + 13824000;  // fp32[4000*32]
  float* sl3     = ws + 13952000;  // fp32[4000*64]
  int*   ib      = (int*)(ws + 14208000);
  int* cnt  = ib + 0;              // [54000] } zeroed; dead after scatter2 ->
  int* cur  = ib + 54000;          // [54000] } overlaid by bf16 Wt
  int* rpc  = ib + 108000;         // [54001] combined row pointers
  int* csum = ib + 162001;         // [64]
  uint2* meta = (uint2*)(ib + 162066);  // [500000] packed (src, ea), 8B-aligned
  // end: ib + 1162066 -> ~61.5 MB

  bf16_t* wtb = (bf16_t*)cnt;      // 432 KB avail, need 256 KB
  bf16_t* wt_l1sg = wtb + 0;
  bf16_t* wt_r1sg = wtb + 16384;
  bf16_t* wt_l1gs = wtb + 32768;
  bf16_t* wt_r1gs = wtb + 49152;
  bf16_t* wt_l3   = wtb + 65536;   // [256*128]
  bf16_t* wt_r3   = wtb + 98304;   // [256*128]

  // zero CSR counters (ws is poisoned 0xAA before every timed call)
  hipMemsetAsync(cnt, 0, 108000 * sizeof(int), stream);

  // ---- phase A: combined CSR build with packed sorted payloads ----
  hist2<<<nblk(NE), 256, 0, stream>>>(sg_dst, gs_dst, cnt);
  int nchunks = (NDST_TOT + 1023) / 1024;            // 53
  scan1<<<nchunks, 1024, 0, stream>>>(cnt, rpc, csum, NDST_TOT);
  scan2<<<1, 64, 0, stream>>>(csum, nchunks);
  scan3<<<nchunks, 1024, 0, stream>>>(rpc, csum, NDST_TOT);
  scatter2<<<nblk(2LL * NE), 256, 0, stream>>>(sg_dst, gs_dst, sg_src, gs_src,
                                               ea_sg, ea_gs, rpc, cur, meta);

  // ---- phase A2: fused weight transpose + x casts (cnt/cur now dead) ----
  {
    PrepArgs pa;
    const float* Wsrc[6] = {Wl1_sg, Wr1_sg, Wl1_gs, Wr1_gs, Wl3_gs, Wr3_gs};
    bf16_t* Wdst[6] = {wt_l1sg, wt_r1sg, wt_l1gs, wt_r1gs, wt_l3, wt_r3};
    int Nn[6] = {128, 128, 128, 128, 256, 256};
    int e0[6] = {0, 16384, 32768, 49152, 65536, 98304};
    for (int i = 0; i < 6; i++) { pa.W[i] = Wsrc[i]; pa.Wt[i] = Wdst[i]; pa.N[i] = Nn[i]; pa.e0[i] = e0[i]; }
    pa.xm = x_mrna; pa.xbm = xb_mrna;
    pa.xg = x_gene; pa.xbg = xb_gene;
    prep<<<7262, 256, 0, stream>>>(pa);
  }

  // ---- phase B: fused layer-1 node GEMMs (bf16 in/out) ----
  {
    GemmArgs<8, 4> ga;
    const bf16_t* Xs[4] = {xb_mrna, xb_gene, xb_gene, xb_mrna};
    const bf16_t* Ws[4] = {wt_l1sg, wt_r1sg, wt_l1gs, wt_r1gs};
    const float* Bs[4] = {bl1_sg, br1_sg, bl1_gs, br1_gs};
    bf16_t* Ys[4] = {xl1_sg, xr1_sg, xl1_gs, xr1_gs};
    int Ms[4] = {NS, NG, NG, NS};
    int b0 = 0;
    for (int i = 0; i < 4; i++) {
      ga.X[i] = Xs[i]; ga.Wt[i] = Ws[i]; ga.Bv[i] = Bs[i]; ga.Y[i] = Ys[i];
      ga.M[i] = Ms[i]; ga.blk0[i] = b0;
      b0 += nrow(Ms[i], 64);
    }
    mfma_gemm_multi<8, 4><<<b0, 256, 0, stream>>>(ga);   // 1690 blocks
  }
  rowgemm<32, bf16_t><<<nrow(NS, 32), 256, 0, stream>>>(xb_mrna, Wsl1, bsl1, sl1, NS);

  // ---- phase C: layer-1 gathers ----
  gat_sg<<<nblk((long long)((NG + 1) / 2) * 64), 256, 0, stream>>>(
      rpc, meta, We1_sg, att1_sg, xl1_sg, xr1_sg, bo1_sg, x1_gene, NG);
  gat_gather4<32, 0, bf16_t><<<NS, 256, 0, stream>>>(
      rpc + NG, meta, We1_gs, att1_gs, xl1_gs, xr1_gs, bo1_gs, sl1, x1_mrna, NS);

  // ---- phase D: fused layer-3 node GEMMs ----
  {
    GemmArgs<16, 2> ga;
    const bf16_t* Xs[2] = {x1_gene, x1_mrna};
    const bf16_t* Ws[2] = {wt_l3, wt_r3};
    const float* Bs[2] = {bl3_gs, br3_gs};
    bf16_t* Ys[2] = {xl3, xr3};
    int Ms[2] = {NG, NS};
    int b0 = 0;
    for (int i = 0; i < 2; i++) {
      ga.X[i] = Xs[i]; ga.Wt[i] = Ws[i]; ga.Bv[i] = Bs[i]; ga.Y[i] = Ys[i];
      ga.M[i] = Ms[i]; ga.blk0[i] = b0;
      b0 += nrow(Ms[i], 64);
    }
    mfma_gemm_multi<16, 2><<<b0, 256, 0, stream>>>(ga);  // 845 blocks
  }
  rowgemm<64, bf16_t><<<nrow(NS, 16), 256, 0, stream>>>(x1_mrna, Wsl3, bsl3, sl3, NS);

  // ---- phase E: layer-3 gather (fused head-mean/self-loop/relu) -> d_out ----
  gat_gather4<64, 1, float><<<NS, 256, 0, stream>>>(
      rpc + NG, meta, We3_gs, att3_gs, xl3, xr3, bo3_gs, sl3, (float*)d_out, NS);
}